// Round 1
// baseline (1409.236 us; speedup 1.0000x reference)
//
#include <hip/hip_runtime.h>

#define NODES 16000
#define EDGES 256000
#define ETOT  272000   // EDGES + NODES self-loops
#define EMB   300
#define KP1   320      // padded EMB (mult of 32)
#define NP1   640      // padded 2*EMB (mult of 64)
#define NGRAPH 64
#define LAYERS 5

typedef unsigned short u16;
typedef __bf16 bf16_t;
typedef bf16_t bf16x8 __attribute__((ext_vector_type(8)));
typedef float f32x4 __attribute__((ext_vector_type(4)));

__device__ inline u16 f2bf(float f) {
    bf16_t b = (bf16_t)f;
    return __builtin_bit_cast(u16, b);
}

// ---------------- CSR build ----------------
__global__ void k_count(const int* __restrict__ ei, int* __restrict__ cnt) {
    int e = blockIdx.x * 256 + threadIdx.x;
    if (e >= ETOT) return;
    int dst = (e < EDGES) ? ei[EDGES + e] : (e - EDGES);
    atomicAdd(&cnt[dst], 1);
}

__global__ void k_scan(const int* cnt_in, int* row_off, int* cursor) {
    __shared__ int s[1024];
    __shared__ int carry;
    int t = threadIdx.x;
    if (t == 0) { carry = 0; row_off[0] = 0; }
    __syncthreads();
    for (int base = 0; base < NODES; base += 1024) {
        int idx = base + t;
        int v = (idx < NODES) ? cnt_in[idx] : 0;
        s[t] = v;
        __syncthreads();
        for (int off = 1; off < 1024; off <<= 1) {
            int add = (t >= off) ? s[t - off] : 0;
            __syncthreads();
            s[t] += add;
            __syncthreads();
        }
        int incl = s[t];
        int c = carry;
        if (idx < NODES) { row_off[idx + 1] = c + incl; cursor[idx] = c + incl - v; }
        __syncthreads();
        if (t == 1023) carry = c + incl;
        __syncthreads();
    }
}

__global__ void k_fill(const int* __restrict__ ei, const int* __restrict__ ea,
                       int* __restrict__ cursor, int* __restrict__ packed) {
    int e = blockIdx.x * 256 + threadIdx.x;
    if (e >= ETOT) return;
    int src, dst, c;
    if (e < EDGES) {
        src = ei[e]; dst = ei[EDGES + e];
        c = ea[e * 2] * 3 + ea[e * 2 + 1];
    } else {
        src = dst = e - EDGES; c = 15;  // self-loop attr (5,0) -> 5*3+0
    }
    int pos = atomicAdd(&cursor[dst], 1);
    packed[pos] = src | (c << 20);
}

// ---------------- setup ----------------
__global__ void k_embed(const int* __restrict__ x, const float* __restrict__ e1,
                        const float* __restrict__ e2, float* __restrict__ h) {
    int id = blockIdx.x * 256 + threadIdx.x;
    if (id >= NODES * EMB) return;
    int i = id / EMB, f = id - i * EMB;
    h[id] = e1[x[2 * i] * EMB + f] + e2[x[2 * i + 1] * EMB + f];
}

__global__ void k_comb(const float* __restrict__ e1, const float* __restrict__ e2,
                       float* __restrict__ comb) {
    int id = blockIdx.x * 256 + threadIdx.x;
    if (id >= LAYERS * 18 * EMB) return;
    int l = id / (18 * EMB);
    int r = id - l * 18 * EMB;
    int c = r / EMB, f = r - c * EMB;
    int a = c / 3, b = c - a * 3;
    comb[id] = e1[(l * 6 + a) * EMB + f] + e2[(l * 3 + b) * EMB + f];
}

// w1bT[l][n][k] = w1[l][k][n] as bf16, zero-padded to [640][320]
__global__ void k_convw1(const float* __restrict__ w1, u16* __restrict__ w1bT) {
    int id = blockIdx.x * 256 + threadIdx.x;
    if (id >= LAYERS * NP1 * KP1) return;
    int l = id / (NP1 * KP1);
    int r = id - l * NP1 * KP1;
    int n = r / KP1, k = r - n * KP1;
    float v = (n < 600 && k < EMB) ? w1[(l * EMB + k) * 600 + n] : 0.f;
    w1bT[id] = f2bf(v);
}

// w2bT[l][n][k] = w2[l][k][n] as bf16, zero-padded to [320][640]
__global__ void k_convw2(const float* __restrict__ w2, u16* __restrict__ w2bT) {
    int id = blockIdx.x * 256 + threadIdx.x;
    if (id >= LAYERS * KP1 * NP1) return;
    int l = id / (KP1 * NP1);
    int r = id - l * KP1 * NP1;
    int n = r / NP1, k = r - n * NP1;
    float v = (n < EMB && k < 600) ? w2[(l * 600 + k) * EMB + n] : 0.f;
    w2bT[id] = f2bf(v);
}

// ---------------- aggregation: one wave per node ----------------
__global__ __launch_bounds__(256) void k_aggregate(
    const float* __restrict__ h, const int* __restrict__ row_off,
    const int* __restrict__ packed, const float* __restrict__ comb,
    u16* __restrict__ aggB) {
    int node = blockIdx.x * 4 + (threadIdx.x >> 6);
    int lane = threadIdx.x & 63;
    int s = row_off[node], e = row_off[node + 1];
    float a0 = 0, a1 = 0, a2 = 0, a3 = 0, a4 = 0;
    int f4 = 256 + lane;
    bool has4 = f4 < EMB;
    for (int p = s; p < e; ++p) {
        int pk = packed[p];
        int src = pk & 0xFFFFF;
        int c = pk >> 20;
        const float* hr = h + (size_t)src * EMB;
        const float* cr = comb + c * EMB;
        a0 += hr[lane]       + cr[lane];
        a1 += hr[lane + 64]  + cr[lane + 64];
        a2 += hr[lane + 128] + cr[lane + 128];
        a3 += hr[lane + 192] + cr[lane + 192];
        if (has4) a4 += hr[f4] + cr[f4];
    }
    u16* o = aggB + (size_t)node * KP1;
    o[lane]       = f2bf(a0);
    o[lane + 64]  = f2bf(a1);
    o[lane + 128] = f2bf(a2);
    o[lane + 192] = f2bf(a3);
    o[lane + 256] = has4 ? f2bf(a4) : (u16)0;
}

// ---------------- bf16 MFMA GEMM: C[M,N] = A[M,K] * Bt[N,K]^T ----------------
// MODE 0: +bias, relu, store bf16 to Cv (ldc stride)
// MODE 1: +bias, store f32 to Cv (stride 300, only cols < 300)
template <int MODE>
__global__ __launch_bounds__(256) void k_gemm(
    const u16* __restrict__ A, const u16* __restrict__ Bt,
    const float* __restrict__ bias, int nbias,
    void* __restrict__ Cv, int ldc, int K) {
    __shared__ __align__(16) u16 Al[64 * 40];
    __shared__ __align__(16) u16 Bl[64 * 40];
    int t = threadIdx.x;
    int m0 = blockIdx.x * 64, n0 = blockIdx.y * 64;
    int lane = t & 63, w = t >> 6;
    int srow = t >> 2, schunk = (t & 3) * 8;
    const u16* Ag = A + (size_t)(m0 + srow) * K + schunk;
    const u16* Bg = Bt + (size_t)(n0 + srow) * K + schunk;
    f32x4 acc[4];
#pragma unroll
    for (int i = 0; i < 4; i++) acc[i] = (f32x4){0.f, 0.f, 0.f, 0.f};
    int arow = w * 16 + (lane & 15);
    int k0 = (lane >> 4) * 8;
    for (int kt = 0; kt < K; kt += 32) {
        uint4 av = *reinterpret_cast<const uint4*>(Ag + kt);
        uint4 bv = *reinterpret_cast<const uint4*>(Bg + kt);
        __syncthreads();
        *reinterpret_cast<uint4*>(&Al[srow * 40 + schunk]) = av;
        *reinterpret_cast<uint4*>(&Bl[srow * 40 + schunk]) = bv;
        __syncthreads();
        bf16x8 af = *reinterpret_cast<const bf16x8*>(&Al[arow * 40 + k0]);
#pragma unroll
        for (int cb = 0; cb < 4; ++cb) {
            bf16x8 bf = *reinterpret_cast<const bf16x8*>(&Bl[(cb * 16 + (lane & 15)) * 40 + k0]);
            acc[cb] = __builtin_amdgcn_mfma_f32_16x16x32_bf16(af, bf, acc[cb], 0, 0, 0);
        }
    }
    int rbase = m0 + w * 16 + ((lane >> 4) * 4);
    int cl = lane & 15;
#pragma unroll
    for (int cb = 0; cb < 4; ++cb) {
        int col = n0 + cb * 16 + cl;
        float bv = (col < nbias) ? bias[col] : 0.f;
#pragma unroll
        for (int j = 0; j < 4; ++j) {
            float v = acc[cb][j] + bv;
            int row = rbase + j;
            if (MODE == 0) {
                v = fmaxf(v, 0.f);
                ((u16*)Cv)[(size_t)row * ldc + col] = f2bf(v);
            } else {
                if (col < EMB) ((float*)Cv)[(size_t)row * EMB + col] = v;
            }
        }
    }
}

// ---------------- batchnorm ----------------
__global__ void k_bnstats(const float* __restrict__ hp, float* __restrict__ sums,
                          float* __restrict__ sumsq) {
    __shared__ float ls[EMB];
    __shared__ float lq[EMB];
    int t = threadIdx.x;
    for (int c = t; c < EMB; c += 256) { ls[c] = 0.f; lq[c] = 0.f; }
    __syncthreads();
    const float* base = hp + (size_t)blockIdx.x * 100 * EMB;
    for (int i = t; i < 100 * EMB; i += 256) {
        float v = base[i];
        int c = i % EMB;
        atomicAdd(&ls[c], v);
        atomicAdd(&lq[c], v * v);
    }
    __syncthreads();
    for (int c = t; c < EMB; c += 256) {
        atomicAdd(&sums[c], ls[c]);
        atomicAdd(&sumsq[c], lq[c]);
    }
}

__global__ void k_bnapply(float* __restrict__ hp, const float* __restrict__ sums,
                          const float* __restrict__ sumsq, const float* __restrict__ g,
                          const float* __restrict__ b, int relu) {
    int id = blockIdx.x * 256 + threadIdx.x;
    if (id >= NODES * EMB) return;
    int c = id % EMB;
    float mean = sums[c] * (1.0f / NODES);
    float var = sumsq[c] * (1.0f / NODES) - mean * mean;
    float rstd = rsqrtf(var + 1e-5f);
    float v = (hp[id] - mean) * rstd * g[c] + b[c];
    if (relu) v = fmaxf(v, 0.f);
    hp[id] = v;
}

// ---------------- pooling + head ----------------
__global__ void k_pool(const float* __restrict__ h, const int* __restrict__ batch,
                       float* __restrict__ hg) {
    __shared__ int se[2];
    int g = blockIdx.x;
    if (threadIdx.x == 0) {
        int lo = 0, hi = NODES;
        while (lo < hi) { int mid = (lo + hi) >> 1; if (batch[mid] < g) lo = mid + 1; else hi = mid; }
        se[0] = lo;
        int lo2 = lo, hi2 = NODES;
        while (lo2 < hi2) { int mid = (lo2 + hi2) >> 1; if (batch[mid] < g + 1) lo2 = mid + 1; else hi2 = mid; }
        se[1] = lo2;
    }
    __syncthreads();
    int s = se[0], e = se[1];
    int c0 = threadIdx.x, c1 = threadIdx.x + 256;
    float a0 = 0.f, a1 = 0.f;
    for (int r = s; r < e; ++r) {
        const float* hr = h + (size_t)r * EMB;
        a0 += hr[c0];
        if (c1 < EMB) a1 += hr[c1];
    }
    float inv = (e > s) ? 1.0f / (float)(e - s) : 0.f;
    hg[g * EMB + c0] = a0 * inv;
    if (c1 < EMB) hg[g * EMB + c1] = a1 * inv;
}

__global__ void k_head_mlp(const float* __restrict__ in, const float* __restrict__ w,
                           const float* __restrict__ bias, float* __restrict__ out,
                           int Kin, int Nout, int act) {
    int id = blockIdx.x * 256 + threadIdx.x;
    if (id >= NGRAPH * Nout) return;
    int g = id / Nout, n = id - g * Nout;
    float acc = bias[n];
    const float* ir = in + (size_t)g * Kin;
    for (int k = 0; k < Kin; ++k) acc += ir[k] * w[(size_t)k * Nout + n];
    if (act) acc = fmaxf(acc, 0.f) + log1pf(expf(-fabsf(acc)));  // softplus, stable
    out[id] = acc;
}

// ---------------- launch ----------------
extern "C" void kernel_launch(void* const* d_in, const int* in_sizes, int n_in,
                              void* d_out, int out_size, void* d_ws, size_t ws_size,
                              hipStream_t stream) {
    const int* x      = (const int*)d_in[0];
    const int* ei     = (const int*)d_in[1];
    const int* ea     = (const int*)d_in[2];
    const int* batch  = (const int*)d_in[3];
    const float* x_emb1 = (const float*)d_in[4];
    const float* x_emb2 = (const float*)d_in[5];
    const float* e1_emb = (const float*)d_in[6];
    const float* e2_emb = (const float*)d_in[7];
    const float* w1   = (const float*)d_in[8];
    const float* b1   = (const float*)d_in[9];
    const float* w2   = (const float*)d_in[10];
    const float* b2   = (const float*)d_in[11];
    const float* bn_g = (const float*)d_in[12];
    const float* bn_b = (const float*)d_in[13];
    const float* feat_w = (const float*)d_in[14];
    const float* feat_b = (const float*)d_in[15];
    const float* hw1  = (const float*)d_in[16];
    const float* hb1  = (const float*)d_in[17];
    const float* hw2  = (const float*)d_in[18];
    const float* hb2  = (const float*)d_in[19];
    const float* hw3  = (const float*)d_in[20];
    const float* hb3  = (const float*)d_in[21];
    float* out = (float*)d_out;

    char* p = (char*)d_ws;
    auto alloc = [&](size_t bytes) -> char* {
        char* r = p;
        p += ((bytes + 255) / 256) * 256;
        return r;
    };
    float* h_a   = (float*)alloc((size_t)NODES * EMB * 4);
    float* h_b   = (float*)alloc((size_t)NODES * EMB * 4);
    u16* aggB    = (u16*)alloc((size_t)NODES * KP1 * 2);
    u16* T       = (u16*)alloc((size_t)NODES * NP1 * 2);
    u16* w1bT    = (u16*)alloc((size_t)LAYERS * NP1 * KP1 * 2);
    u16* w2bT    = (u16*)alloc((size_t)LAYERS * KP1 * NP1 * 2);
    float* comb  = (float*)alloc((size_t)LAYERS * 18 * EMB * 4);
    int* row_off = (int*)alloc((NODES + 1) * 4);
    int* cursor  = (int*)alloc(NODES * 4);
    int* packed  = (int*)alloc((size_t)ETOT * 4);
    float* stats = (float*)alloc(2 * 304 * 4);
    float* hg    = (float*)alloc((size_t)NGRAPH * EMB * 4);
    float* pb1   = (float*)alloc((size_t)NGRAPH * 256 * 4);
    float* pb2   = (float*)alloc((size_t)NGRAPH * 256 * 4);
    if ((size_t)(p - (char*)d_ws) > ws_size) return;  // workspace too small

    // CSR build (once; shared across layers)
    hipMemsetAsync(cursor, 0, NODES * 4, stream);
    k_count<<<(ETOT + 255) / 256, 256, 0, stream>>>(ei, cursor);
    k_scan<<<1, 1024, 0, stream>>>(cursor, row_off, cursor);
    k_fill<<<(ETOT + 255) / 256, 256, 0, stream>>>(ei, ea, cursor, packed);

    k_embed<<<(NODES * EMB + 255) / 256, 256, 0, stream>>>(x, x_emb1, x_emb2, h_a);
    k_comb<<<(LAYERS * 18 * EMB + 255) / 256, 256, 0, stream>>>(e1_emb, e2_emb, comb);
    k_convw1<<<(LAYERS * NP1 * KP1 + 255) / 256, 256, 0, stream>>>(w1, w1bT);
    k_convw2<<<(LAYERS * KP1 * NP1 + 255) / 256, 256, 0, stream>>>(w2, w2bT);

    for (int l = 0; l < LAYERS; ++l) {
        const float* h_in = (l & 1) ? h_b : h_a;
        float* h_out      = (l & 1) ? h_a : h_b;
        k_aggregate<<<NODES / 4, 256, 0, stream>>>(h_in, row_off, packed,
                                                   comb + (size_t)l * 18 * EMB, aggB);
        k_gemm<0><<<dim3(NODES / 64, NP1 / 64), 256, 0, stream>>>(
            aggB, w1bT + (size_t)l * NP1 * KP1, b1 + l * 600, 600, T, NP1, KP1);
        k_gemm<1><<<dim3(NODES / 64, KP1 / 64), 256, 0, stream>>>(
            T, w2bT + (size_t)l * KP1 * NP1, b2 + l * EMB, EMB, h_out, 0, NP1);
        hipMemsetAsync(stats, 0, 2 * 304 * 4, stream);
        k_bnstats<<<NODES / 100, 256, 0, stream>>>(h_out, stats, stats + 304);
        k_bnapply<<<(NODES * EMB + 255) / 256, 256, 0, stream>>>(
            h_out, stats, stats + 304, bn_g + l * EMB, bn_b + l * EMB,
            (l < LAYERS - 1) ? 1 : 0);
    }

    const float* h_fin = h_b;  // layer 4 wrote h_b
    k_pool<<<NGRAPH, 256, 0, stream>>>(h_fin, batch, hg);
    k_head_mlp<<<(NGRAPH * 512 + 255) / 256, 256, 0, stream>>>(hg, feat_w, feat_b, out, EMB, 512, 0);
    k_head_mlp<<<(NGRAPH * 256 + 255) / 256, 256, 0, stream>>>(out, hw1, hb1, pb1, 512, 256, 1);
    k_head_mlp<<<(NGRAPH * 256 + 255) / 256, 256, 0, stream>>>(pb1, hw2, hb2, pb2, 256, 256, 1);
    k_head_mlp<<<1, 256, 0, stream>>>(pb2, hw3, hb3, out + NGRAPH * 512, 256, 2, 0);
}

// Round 2
// 1193.877 us; speedup vs baseline: 1.1804x; 1.1804x over previous
//
#include <hip/hip_runtime.h>

#define NODES 16000
#define EDGES 256000
#define ETOT  272000   // EDGES + NODES self-loops
#define EMB   300
#define KP1   320      // padded EMB (mult of 32)
#define NP1   640      // padded 2*EMB (mult of 64)
#define NGRAPH 64
#define LAYERS 5

typedef unsigned short u16;
typedef __bf16 bf16_t;
typedef bf16_t bf16x8 __attribute__((ext_vector_type(8)));
typedef float f32x4 __attribute__((ext_vector_type(4)));

__device__ inline u16 f2bf(float f) {
    bf16_t b = (bf16_t)f;
    return __builtin_bit_cast(u16, b);
}

__device__ inline float softplus_f(float x) {
    return fmaxf(x, 0.f) + log1pf(expf(-fabsf(x)));
}

// ---------------- CSR build ----------------
__global__ void k_count(const int* __restrict__ ei, int* __restrict__ cnt) {
    int e = blockIdx.x * 256 + threadIdx.x;
    if (e >= ETOT) return;
    int dst = (e < EDGES) ? ei[EDGES + e] : (e - EDGES);
    atomicAdd(&cnt[dst], 1);
}

__global__ void k_scan(const int* cnt_in, int* row_off, int* cursor) {
    __shared__ int s[1024];
    __shared__ int carry;
    int t = threadIdx.x;
    if (t == 0) { carry = 0; row_off[0] = 0; }
    __syncthreads();
    for (int base = 0; base < NODES; base += 1024) {
        int idx = base + t;
        int v = (idx < NODES) ? cnt_in[idx] : 0;
        s[t] = v;
        __syncthreads();
        for (int off = 1; off < 1024; off <<= 1) {
            int add = (t >= off) ? s[t - off] : 0;
            __syncthreads();
            s[t] += add;
            __syncthreads();
        }
        int incl = s[t];
        int c = carry;
        if (idx < NODES) { row_off[idx + 1] = c + incl; cursor[idx] = c + incl - v; }
        __syncthreads();
        if (t == 1023) carry = c + incl;
        __syncthreads();
    }
}

__global__ void k_fill(const int* __restrict__ ei, const int* __restrict__ ea,
                       int* __restrict__ cursor, int* __restrict__ packed) {
    int e = blockIdx.x * 256 + threadIdx.x;
    if (e >= ETOT) return;
    int src, dst, c;
    if (e < EDGES) {
        src = ei[e]; dst = ei[EDGES + e];
        c = ea[e * 2] * 3 + ea[e * 2 + 1];
    } else {
        src = dst = e - EDGES; c = 15;  // self-loop attr (5,0) -> 5*3+0
    }
    int pos = atomicAdd(&cursor[dst], 1);
    packed[pos] = src | (c << 20);
}

// ---------------- setup ----------------
__global__ void k_embed(const int* __restrict__ x, const float* __restrict__ e1,
                        const float* __restrict__ e2, float* __restrict__ h) {
    int id = blockIdx.x * 256 + threadIdx.x;
    if (id >= NODES * EMB) return;
    int i = id / EMB, f = id - i * EMB;
    h[id] = e1[x[2 * i] * EMB + f] + e2[x[2 * i + 1] * EMB + f];
}

__global__ void k_comb(const float* __restrict__ e1, const float* __restrict__ e2,
                       float* __restrict__ comb) {
    int id = blockIdx.x * 256 + threadIdx.x;
    if (id >= LAYERS * 18 * EMB) return;
    int l = id / (18 * EMB);
    int r = id - l * 18 * EMB;
    int c = r / EMB, f = r - c * EMB;
    int a = c / 3, b = c - a * 3;
    comb[id] = e1[(l * 6 + a) * EMB + f] + e2[(l * 3 + b) * EMB + f];
}

// w1bT[l][n][k] = w1[l][k][n] as bf16, zero-padded to [640][320]
__global__ void k_convw1(const float* __restrict__ w1, u16* __restrict__ w1bT) {
    int id = blockIdx.x * 256 + threadIdx.x;
    if (id >= LAYERS * NP1 * KP1) return;
    int l = id / (NP1 * KP1);
    int r = id - l * NP1 * KP1;
    int n = r / KP1, k = r - n * KP1;
    float v = (n < 600 && k < EMB) ? w1[(l * EMB + k) * 600 + n] : 0.f;
    w1bT[id] = f2bf(v);
}

// w2bT[l][n][k] = w2[l][k][n] as bf16, zero-padded to [320][640]
__global__ void k_convw2(const float* __restrict__ w2, u16* __restrict__ w2bT) {
    int id = blockIdx.x * 256 + threadIdx.x;
    if (id >= LAYERS * KP1 * NP1) return;
    int l = id / (KP1 * NP1);
    int r = id - l * KP1 * NP1;
    int n = r / NP1, k = r - n * NP1;
    float v = (n < EMB && k < 600) ? w2[(l * 600 + k) * EMB + n] : 0.f;
    w2bT[id] = f2bf(v);
}

// ---------------- aggregation: one wave per node ----------------
__global__ __launch_bounds__(256) void k_aggregate(
    const float* __restrict__ h, const int* __restrict__ row_off,
    const int* __restrict__ packed, const float* __restrict__ comb,
    u16* __restrict__ aggB) {
    int node = blockIdx.x * 4 + (threadIdx.x >> 6);
    int lane = threadIdx.x & 63;
    int s = row_off[node], e = row_off[node + 1];
    float a0 = 0, a1 = 0, a2 = 0, a3 = 0, a4 = 0;
    int f4 = 256 + lane;
    bool has4 = f4 < EMB;
    for (int p = s; p < e; ++p) {
        int pk = packed[p];
        int src = pk & 0xFFFFF;
        int c = pk >> 20;
        const float* hr = h + (size_t)src * EMB;
        const float* cr = comb + c * EMB;
        a0 += hr[lane]       + cr[lane];
        a1 += hr[lane + 64]  + cr[lane + 64];
        a2 += hr[lane + 128] + cr[lane + 128];
        a3 += hr[lane + 192] + cr[lane + 192];
        if (has4) a4 += hr[f4] + cr[f4];
    }
    u16* o = aggB + (size_t)node * KP1;
    o[lane]       = f2bf(a0);
    o[lane + 64]  = f2bf(a1);
    o[lane + 128] = f2bf(a2);
    o[lane + 192] = f2bf(a3);
    o[lane + 256] = has4 ? f2bf(a4) : (u16)0;
}

// ---------------- bf16 MFMA GEMM: C[M,N] = A[M,K] * Bt[N,K]^T ----------------
// MODE 0: +bias, relu, store bf16 to Cv (ldc stride)
// MODE 1: +bias, store f32 to Cv (stride 300, only cols < 300)
template <int MODE>
__global__ __launch_bounds__(256) void k_gemm(
    const u16* __restrict__ A, const u16* __restrict__ Bt,
    const float* __restrict__ bias, int nbias,
    void* __restrict__ Cv, int ldc, int K) {
    __shared__ __align__(16) u16 Al[64 * 40];
    __shared__ __align__(16) u16 Bl[64 * 40];
    int t = threadIdx.x;
    int m0 = blockIdx.x * 64, n0 = blockIdx.y * 64;
    int lane = t & 63, w = t >> 6;
    int srow = t >> 2, schunk = (t & 3) * 8;
    const u16* Ag = A + (size_t)(m0 + srow) * K + schunk;
    const u16* Bg = Bt + (size_t)(n0 + srow) * K + schunk;
    f32x4 acc[4];
#pragma unroll
    for (int i = 0; i < 4; i++) acc[i] = (f32x4){0.f, 0.f, 0.f, 0.f};
    int arow = w * 16 + (lane & 15);
    int k0 = (lane >> 4) * 8;
    for (int kt = 0; kt < K; kt += 32) {
        uint4 av = *reinterpret_cast<const uint4*>(Ag + kt);
        uint4 bv = *reinterpret_cast<const uint4*>(Bg + kt);
        __syncthreads();
        *reinterpret_cast<uint4*>(&Al[srow * 40 + schunk]) = av;
        *reinterpret_cast<uint4*>(&Bl[srow * 40 + schunk]) = bv;
        __syncthreads();
        bf16x8 af = *reinterpret_cast<const bf16x8*>(&Al[arow * 40 + k0]);
#pragma unroll
        for (int cb = 0; cb < 4; ++cb) {
            bf16x8 bf = *reinterpret_cast<const bf16x8*>(&Bl[(cb * 16 + (lane & 15)) * 40 + k0]);
            acc[cb] = __builtin_amdgcn_mfma_f32_16x16x32_bf16(af, bf, acc[cb], 0, 0, 0);
        }
    }
    int rbase = m0 + w * 16 + ((lane >> 4) * 4);
    int cl = lane & 15;
#pragma unroll
    for (int cb = 0; cb < 4; ++cb) {
        int col = n0 + cb * 16 + cl;
        float bv = (col < nbias) ? bias[col] : 0.f;
#pragma unroll
        for (int j = 0; j < 4; ++j) {
            float v = acc[cb][j] + bv;
            int row = rbase + j;
            if (MODE == 0) {
                v = fmaxf(v, 0.f);
                ((u16*)Cv)[(size_t)row * ldc + col] = f2bf(v);
            } else {
                if (col < EMB) ((float*)Cv)[(size_t)row * EMB + col] = v;
            }
        }
    }
}

// ---------------- batchnorm ----------------
__global__ void k_bnstats(const float* __restrict__ hp, float* __restrict__ sums,
                          float* __restrict__ sumsq) {
    __shared__ float ls[EMB];
    __shared__ float lq[EMB];
    int t = threadIdx.x;
    for (int c = t; c < EMB; c += 256) { ls[c] = 0.f; lq[c] = 0.f; }
    __syncthreads();
    const float* base = hp + (size_t)blockIdx.x * 100 * EMB;
    for (int i = t; i < 100 * EMB; i += 256) {
        float v = base[i];
        int c = i % EMB;
        atomicAdd(&ls[c], v);
        atomicAdd(&lq[c], v * v);
    }
    __syncthreads();
    for (int c = t; c < EMB; c += 256) {
        atomicAdd(&sums[c], ls[c]);
        atomicAdd(&sumsq[c], lq[c]);
    }
}

__global__ void k_bnapply(float* __restrict__ hp, const float* __restrict__ sums,
                          const float* __restrict__ sumsq, const float* __restrict__ g,
                          const float* __restrict__ b, int relu) {
    int id = blockIdx.x * 256 + threadIdx.x;
    if (id >= NODES * EMB) return;
    int c = id % EMB;
    float mean = sums[c] * (1.0f / NODES);
    float var = sumsq[c] * (1.0f / NODES) - mean * mean;
    float rstd = rsqrtf(var + 1e-5f);
    float v = (hp[id] - mean) * rstd * g[c] + b[c];
    if (relu) v = fmaxf(v, 0.f);
    hp[id] = v;
}

// ---------------- fused pool + feat + head MLP: one block per graph ----------------
__global__ __launch_bounds__(256) void k_pool_head(
    const float* __restrict__ h, const int* __restrict__ batch,
    const float* __restrict__ feat_w, const float* __restrict__ feat_b,
    const float* __restrict__ hw1, const float* __restrict__ hb1,
    const float* __restrict__ hw2, const float* __restrict__ hb2,
    const float* __restrict__ hw3, const float* __restrict__ hb3,
    float* __restrict__ out) {
    __shared__ float s_hg[EMB];
    __shared__ float s_hf[512];
    __shared__ float s_p[256];
    __shared__ float red[2][4];
    __shared__ int se[2];
    int g = blockIdx.x;
    int t = threadIdx.x;
    if (t == 0) {
        int lo = 0, hi = NODES;
        while (lo < hi) { int mid = (lo + hi) >> 1; if (batch[mid] < g) lo = mid + 1; else hi = mid; }
        se[0] = lo;
        int lo2 = lo, hi2 = NODES;
        while (lo2 < hi2) { int mid = (lo2 + hi2) >> 1; if (batch[mid] < g + 1) lo2 = mid + 1; else hi2 = mid; }
        se[1] = lo2;
    }
    __syncthreads();
    int s = se[0], e = se[1];
    // ---- pool: mean over rows [s,e), thread t owns cols t and t+256 ----
    float a0 = 0.f, a1 = 0.f;
    bool has1 = (t + 256) < EMB;
    for (int r = s; r < e; ++r) {
        const float* hr = h + (size_t)r * EMB;
        a0 += hr[t];
        if (has1) a1 += hr[t + 256];
    }
    float inv = (e > s) ? 1.0f / (float)(e - s) : 0.f;
    if (t < EMB) s_hg[t] = a0 * inv;
    if (has1) s_hg[t + 256] = a1 * inv;
    __syncthreads();
    // ---- hf = hg @ feat_w + feat_b : thread t owns cols t, t+256 ----
    float f0 = feat_b[t], f1 = feat_b[t + 256];
#pragma unroll 4
    for (int k = 0; k < EMB; ++k) {
        float hv = s_hg[k];
        f0 += hv * feat_w[k * 512 + t];
        f1 += hv * feat_w[k * 512 + 256 + t];
    }
    s_hf[t] = f0;
    s_hf[t + 256] = f1;
    out[(size_t)g * 512 + t] = f0;
    out[(size_t)g * 512 + 256 + t] = f1;
    __syncthreads();
    // ---- p1 = softplus(hf @ hw1 + hb1) : thread t owns col t (256 cols) ----
    float p = hb1[t];
#pragma unroll 4
    for (int k = 0; k < 512; ++k) p += s_hf[k] * hw1[k * 256 + t];
    p = softplus_f(p);
    s_p[t] = p;
    __syncthreads();
    // ---- p2 = softplus(p1 @ hw2 + hb2) ----
    float q = hb2[t];
#pragma unroll 4
    for (int k = 0; k < 256; ++k) q += s_p[k] * hw2[k * 256 + t];
    q = softplus_f(q);
    // ---- pred = p2 @ hw3 + hb3 : block-wide reduction of 2 outputs ----
    float r0 = q * hw3[t * 2 + 0];
    float r1 = q * hw3[t * 2 + 1];
#pragma unroll
    for (int off = 32; off > 0; off >>= 1) {
        r0 += __shfl_down(r0, off);
        r1 += __shfl_down(r1, off);
    }
    if ((t & 63) == 0) { red[0][t >> 6] = r0; red[1][t >> 6] = r1; }
    __syncthreads();
    if (t == 0) {
        float t0 = red[0][0] + red[0][1] + red[0][2] + red[0][3] + hb3[0];
        float t1 = red[1][0] + red[1][1] + red[1][2] + red[1][3] + hb3[1];
        out[(size_t)NGRAPH * 512 + g * 2 + 0] = t0;
        out[(size_t)NGRAPH * 512 + g * 2 + 1] = t1;
    }
}

// ---------------- launch ----------------
extern "C" void kernel_launch(void* const* d_in, const int* in_sizes, int n_in,
                              void* d_out, int out_size, void* d_ws, size_t ws_size,
                              hipStream_t stream) {
    const int* x      = (const int*)d_in[0];
    const int* ei     = (const int*)d_in[1];
    const int* ea     = (const int*)d_in[2];
    const int* batch  = (const int*)d_in[3];
    const float* x_emb1 = (const float*)d_in[4];
    const float* x_emb2 = (const float*)d_in[5];
    const float* e1_emb = (const float*)d_in[6];
    const float* e2_emb = (const float*)d_in[7];
    const float* w1   = (const float*)d_in[8];
    const float* b1   = (const float*)d_in[9];
    const float* w2   = (const float*)d_in[10];
    const float* b2   = (const float*)d_in[11];
    const float* bn_g = (const float*)d_in[12];
    const float* bn_b = (const float*)d_in[13];
    const float* feat_w = (const float*)d_in[14];
    const float* feat_b = (const float*)d_in[15];
    const float* hw1  = (const float*)d_in[16];
    const float* hb1  = (const float*)d_in[17];
    const float* hw2  = (const float*)d_in[18];
    const float* hb2  = (const float*)d_in[19];
    const float* hw3  = (const float*)d_in[20];
    const float* hb3  = (const float*)d_in[21];
    float* out = (float*)d_out;

    char* p = (char*)d_ws;
    auto alloc = [&](size_t bytes) -> char* {
        char* r = p;
        p += ((bytes + 255) / 256) * 256;
        return r;
    };
    float* h_a   = (float*)alloc((size_t)NODES * EMB * 4);
    float* h_b   = (float*)alloc((size_t)NODES * EMB * 4);
    u16* aggB    = (u16*)alloc((size_t)NODES * KP1 * 2);
    u16* T       = (u16*)alloc((size_t)NODES * NP1 * 2);
    u16* w1bT    = (u16*)alloc((size_t)LAYERS * NP1 * KP1 * 2);
    u16* w2bT    = (u16*)alloc((size_t)LAYERS * KP1 * NP1 * 2);
    float* comb  = (float*)alloc((size_t)LAYERS * 18 * EMB * 4);
    int* row_off = (int*)alloc((NODES + 1) * 4);
    int* cursor  = (int*)alloc(NODES * 4);
    int* packed  = (int*)alloc((size_t)ETOT * 4);
    float* stats = (float*)alloc(2 * 304 * 4);
    if ((size_t)(p - (char*)d_ws) > ws_size) return;  // workspace too small

    // CSR build (once; shared across layers)
    hipMemsetAsync(cursor, 0, NODES * 4, stream);
    k_count<<<(ETOT + 255) / 256, 256, 0, stream>>>(ei, cursor);
    k_scan<<<1, 1024, 0, stream>>>(cursor, row_off, cursor);
    k_fill<<<(ETOT + 255) / 256, 256, 0, stream>>>(ei, ea, cursor, packed);

    k_embed<<<(NODES * EMB + 255) / 256, 256, 0, stream>>>(x, x_emb1, x_emb2, h_a);
    k_comb<<<(LAYERS * 18 * EMB + 255) / 256, 256, 0, stream>>>(e1_emb, e2_emb, comb);
    k_convw1<<<(LAYERS * NP1 * KP1 + 255) / 256, 256, 0, stream>>>(w1, w1bT);
    k_convw2<<<(LAYERS * KP1 * NP1 + 255) / 256, 256, 0, stream>>>(w2, w2bT);

    for (int l = 0; l < LAYERS; ++l) {
        const float* h_in = (l & 1) ? h_b : h_a;
        float* h_out      = (l & 1) ? h_a : h_b;
        k_aggregate<<<NODES / 4, 256, 0, stream>>>(h_in, row_off, packed,
                                                   comb + (size_t)l * 18 * EMB, aggB);
        k_gemm<0><<<dim3(NODES / 64, NP1 / 64), 256, 0, stream>>>(
            aggB, w1bT + (size_t)l * NP1 * KP1, b1 + l * 600, 600, T, NP1, KP1);
        k_gemm<1><<<dim3(NODES / 64, KP1 / 64), 256, 0, stream>>>(
            T, w2bT + (size_t)l * KP1 * NP1, b2 + l * EMB, EMB, h_out, 0, NP1);
        hipMemsetAsync(stats, 0, 2 * 304 * 4, stream);
        k_bnstats<<<NODES / 100, 256, 0, stream>>>(h_out, stats, stats + 304);
        k_bnapply<<<(NODES * EMB + 255) / 256, 256, 0, stream>>>(
            h_out, stats, stats + 304, bn_g + l * EMB, bn_b + l * EMB,
            (l < LAYERS - 1) ? 1 : 0);
    }

    const float* h_fin = h_b;  // layer 4 wrote h_b
    k_pool_head<<<NGRAPH, 256, 0, stream>>>(h_fin, batch, feat_w, feat_b,
                                            hw1, hb1, hw2, hb2, hw3, hb3, out);
}

// Round 3
// 1104.875 us; speedup vs baseline: 1.2755x; 1.0806x over previous
//
#include <hip/hip_runtime.h>

#define NODES 16000
#define EDGES 256000
#define ETOT  272000   // EDGES + NODES self-loops
#define EMB   300
#define KP1   320      // padded EMB (mult of 32)
#define NP1   640      // padded 2*EMB (mult of 64)
#define NGRAPH 64
#define LAYERS 5

typedef unsigned short u16;
typedef __bf16 bf16_t;
typedef bf16_t bf16x8 __attribute__((ext_vector_type(8)));
typedef float f32x4 __attribute__((ext_vector_type(4)));

__device__ inline u16 f2bf(float f) {
    bf16_t b = (bf16_t)f;
    return __builtin_bit_cast(u16, b);
}

__device__ inline float softplus_f(float x) {
    return fmaxf(x, 0.f) + log1pf(expf(-fabsf(x)));
}

// ---------------- CSR build ----------------
__global__ void k_count(const int* __restrict__ ei, int* __restrict__ cnt) {
    int e = blockIdx.x * 256 + threadIdx.x;
    if (e >= ETOT) return;
    int dst = (e < EDGES) ? ei[EDGES + e] : (e - EDGES);
    atomicAdd(&cnt[dst], 1);
}

__global__ void k_scan(const int* cnt_in, int* row_off, int* cursor) {
    __shared__ int s[1024];
    __shared__ int carry;
    int t = threadIdx.x;
    if (t == 0) { carry = 0; row_off[0] = 0; }
    __syncthreads();
    for (int base = 0; base < NODES; base += 1024) {
        int idx = base + t;
        int v = (idx < NODES) ? cnt_in[idx] : 0;
        s[t] = v;
        __syncthreads();
        for (int off = 1; off < 1024; off <<= 1) {
            int add = (t >= off) ? s[t - off] : 0;
            __syncthreads();
            s[t] += add;
            __syncthreads();
        }
        int incl = s[t];
        int c = carry;
        if (idx < NODES) { row_off[idx + 1] = c + incl; cursor[idx] = c + incl - v; }
        __syncthreads();
        if (t == 1023) carry = c + incl;
        __syncthreads();
    }
}

__global__ void k_fill(const int* __restrict__ ei, const int* __restrict__ ea,
                       int* __restrict__ cursor, int* __restrict__ packed) {
    int e = blockIdx.x * 256 + threadIdx.x;
    if (e >= ETOT) return;
    int src, dst, c;
    if (e < EDGES) {
        src = ei[e]; dst = ei[EDGES + e];
        c = ea[e * 2] * 3 + ea[e * 2 + 1];
    } else {
        src = dst = e - EDGES; c = 15;  // self-loop attr (5,0) -> 5*3+0
    }
    int pos = atomicAdd(&cursor[dst], 1);
    packed[pos] = src | (c << 20);
}

// ---------------- setup ----------------
__global__ void k_embed(const int* __restrict__ x, const float* __restrict__ e1,
                        const float* __restrict__ e2, float* __restrict__ h) {
    int id = blockIdx.x * 256 + threadIdx.x;
    if (id >= NODES * EMB) return;
    int i = id / EMB, f = id - i * EMB;
    h[id] = e1[x[2 * i] * EMB + f] + e2[x[2 * i + 1] * EMB + f];
}

__global__ void k_comb(const float* __restrict__ e1, const float* __restrict__ e2,
                       float* __restrict__ comb) {
    int id = blockIdx.x * 256 + threadIdx.x;
    if (id >= LAYERS * 18 * EMB) return;
    int l = id / (18 * EMB);
    int r = id - l * 18 * EMB;
    int c = r / EMB, f = r - c * EMB;
    int a = c / 3, b = c - a * 3;
    comb[id] = e1[(l * 6 + a) * EMB + f] + e2[(l * 3 + b) * EMB + f];
}

// w1bT[l][n][k] = w1[l][k][n] as bf16, zero-padded to [640][320]
__global__ void k_convw1(const float* __restrict__ w1, u16* __restrict__ w1bT) {
    int id = blockIdx.x * 256 + threadIdx.x;
    if (id >= LAYERS * NP1 * KP1) return;
    int l = id / (NP1 * KP1);
    int r = id - l * NP1 * KP1;
    int n = r / KP1, k = r - n * KP1;
    float v = (n < 600 && k < EMB) ? w1[(l * EMB + k) * 600 + n] : 0.f;
    w1bT[id] = f2bf(v);
}

// w2bT[l][n][k] = w2[l][k][n] as bf16, zero-padded to [320][640]
__global__ void k_convw2(const float* __restrict__ w2, u16* __restrict__ w2bT) {
    int id = blockIdx.x * 256 + threadIdx.x;
    if (id >= LAYERS * KP1 * NP1) return;
    int l = id / (KP1 * NP1);
    int r = id - l * KP1 * NP1;
    int n = r / NP1, k = r - n * NP1;
    float v = (n < EMB && k < 600) ? w2[(l * 600 + k) * EMB + n] : 0.f;
    w2bT[id] = f2bf(v);
}

// ---------------- aggregation: one wave per node ----------------
__global__ __launch_bounds__(256) void k_aggregate(
    const float* __restrict__ h, const int* __restrict__ row_off,
    const int* __restrict__ packed, const float* __restrict__ comb,
    u16* __restrict__ aggB) {
    int node = blockIdx.x * 4 + (threadIdx.x >> 6);
    int lane = threadIdx.x & 63;
    int s = row_off[node], e = row_off[node + 1];
    float a0 = 0, a1 = 0, a2 = 0, a3 = 0, a4 = 0;
    int f4 = 256 + lane;
    bool has4 = f4 < EMB;
    for (int p = s; p < e; ++p) {
        int pk = packed[p];
        int src = pk & 0xFFFFF;
        int c = pk >> 20;
        const float* hr = h + (size_t)src * EMB;
        const float* cr = comb + c * EMB;
        a0 += hr[lane]       + cr[lane];
        a1 += hr[lane + 64]  + cr[lane + 64];
        a2 += hr[lane + 128] + cr[lane + 128];
        a3 += hr[lane + 192] + cr[lane + 192];
        if (has4) a4 += hr[f4] + cr[f4];
    }
    u16* o = aggB + (size_t)node * KP1;
    o[lane]       = f2bf(a0);
    o[lane + 64]  = f2bf(a1);
    o[lane + 128] = f2bf(a2);
    o[lane + 192] = f2bf(a3);
    o[lane + 256] = has4 ? f2bf(a4) : (u16)0;
}

// ---------------- bf16 MFMA GEMM: C[M,N] = A[M,K] * Bt[N,K]^T ----------------
// MODE 0: +bias, relu, store bf16 to Cv (ldc stride)
// MODE 1: +bias, store f32 to Cv (stride 300, only cols < 300)
template <int MODE>
__global__ __launch_bounds__(256) void k_gemm(
    const u16* __restrict__ A, const u16* __restrict__ Bt,
    const float* __restrict__ bias, int nbias,
    void* __restrict__ Cv, int ldc, int K) {
    __shared__ __align__(16) u16 Al[64 * 40];
    __shared__ __align__(16) u16 Bl[64 * 40];
    int t = threadIdx.x;
    int m0 = blockIdx.x * 64, n0 = blockIdx.y * 64;
    int lane = t & 63, w = t >> 6;
    int srow = t >> 2, schunk = (t & 3) * 8;
    const u16* Ag = A + (size_t)(m0 + srow) * K + schunk;
    const u16* Bg = Bt + (size_t)(n0 + srow) * K + schunk;
    f32x4 acc[4];
#pragma unroll
    for (int i = 0; i < 4; i++) acc[i] = (f32x4){0.f, 0.f, 0.f, 0.f};
    int arow = w * 16 + (lane & 15);
    int k0 = (lane >> 4) * 8;
    for (int kt = 0; kt < K; kt += 32) {
        uint4 av = *reinterpret_cast<const uint4*>(Ag + kt);
        uint4 bv = *reinterpret_cast<const uint4*>(Bg + kt);
        __syncthreads();
        *reinterpret_cast<uint4*>(&Al[srow * 40 + schunk]) = av;
        *reinterpret_cast<uint4*>(&Bl[srow * 40 + schunk]) = bv;
        __syncthreads();
        bf16x8 af = *reinterpret_cast<const bf16x8*>(&Al[arow * 40 + k0]);
#pragma unroll
        for (int cb = 0; cb < 4; ++cb) {
            bf16x8 bf = *reinterpret_cast<const bf16x8*>(&Bl[(cb * 16 + (lane & 15)) * 40 + k0]);
            acc[cb] = __builtin_amdgcn_mfma_f32_16x16x32_bf16(af, bf, acc[cb], 0, 0, 0);
        }
    }
    int rbase = m0 + w * 16 + ((lane >> 4) * 4);
    int cl = lane & 15;
#pragma unroll
    for (int cb = 0; cb < 4; ++cb) {
        int col = n0 + cb * 16 + cl;
        float bv = (col < nbias) ? bias[col] : 0.f;
#pragma unroll
        for (int j = 0; j < 4; ++j) {
            float v = acc[cb][j] + bv;
            int row = rbase + j;
            if (MODE == 0) {
                v = fmaxf(v, 0.f);
                ((u16*)Cv)[(size_t)row * ldc + col] = f2bf(v);
            } else {
                if (col < EMB) ((float*)Cv)[(size_t)row * EMB + col] = v;
            }
        }
    }
}

// ---------------- batchnorm ----------------
__global__ void k_bnstats(const float* __restrict__ hp, float* __restrict__ sums,
                          float* __restrict__ sumsq) {
    __shared__ float ls[EMB];
    __shared__ float lq[EMB];
    int t = threadIdx.x;
    for (int c = t; c < EMB; c += 256) { ls[c] = 0.f; lq[c] = 0.f; }
    __syncthreads();
    const float* base = hp + (size_t)blockIdx.x * 100 * EMB;
    for (int i = t; i < 100 * EMB; i += 256) {
        float v = base[i];
        int c = i % EMB;
        atomicAdd(&ls[c], v);
        atomicAdd(&lq[c], v * v);
    }
    __syncthreads();
    for (int c = t; c < EMB; c += 256) {
        atomicAdd(&sums[c], ls[c]);
        atomicAdd(&sumsq[c], lq[c]);
    }
}

__global__ void k_bnapply(float* __restrict__ hp, const float* __restrict__ sums,
                          const float* __restrict__ sumsq, const float* __restrict__ g,
                          const float* __restrict__ b, int relu) {
    int id = blockIdx.x * 256 + threadIdx.x;
    if (id >= NODES * EMB) return;
    int c = id % EMB;
    float mean = sums[c] * (1.0f / NODES);
    float var = sumsq[c] * (1.0f / NODES) - mean * mean;
    float rstd = rsqrtf(var + 1e-5f);
    float v = (hp[id] - mean) * rstd * g[c] + b[c];
    if (relu) v = fmaxf(v, 0.f);
    hp[id] = v;
}

// ---------------- tail: graph offsets, pool, head GEMMs ----------------
__global__ void k_goff(const int* __restrict__ batch, int* __restrict__ goff) {
    int t = threadIdx.x;
    if (t > NGRAPH) return;
    int lo = 0, hi = NODES;
    while (lo < hi) { int mid = (lo + hi) >> 1; if (batch[mid] < t) lo = mid + 1; else hi = mid; }
    goff[t] = lo;
}

// grid (NGRAPH, 5): block = 4 waves x 64 lanes; wave w sums rows s+w, s+w+4, ...
__global__ __launch_bounds__(256) void k_pool(const float* __restrict__ h,
                                              const int* __restrict__ goff,
                                              float* __restrict__ hg) {
    __shared__ float red[4][64];
    int g = blockIdx.x;
    int col = blockIdx.y * 64 + (threadIdx.x & 63);
    int w = threadIdx.x >> 6;
    int s = goff[g], e = goff[g + 1];
    float a = 0.f;
    bool ok = col < EMB;
    if (ok) {
        for (int r = s + w; r < e; r += 4) a += h[(size_t)r * EMB + col];
    }
    red[w][threadIdx.x & 63] = a;
    __syncthreads();
    if (w == 0 && ok) {
        float v = red[0][threadIdx.x] + red[1][threadIdx.x] +
                  red[2][threadIdx.x] + red[3][threadIdx.x];
        float inv = (e > s) ? 1.0f / (float)(e - s) : 0.f;
        hg[(size_t)g * EMB + col] = v * inv;
    }
}

// C[row, col] = act(A[row,:K] @ W[:K, col] + b[col]); grid (M, N/64), block 256.
// wave w accumulates k = w, w+4, ...; LDS reduce across the 4 waves.
template <int ACT>  // 0: none, 1: softplus
__global__ __launch_bounds__(256) void k_small_mm(
    const float* __restrict__ A, const float* __restrict__ W,
    const float* __restrict__ bias, float* __restrict__ C, int N, int K) {
    __shared__ float red[4][64];
    int row = blockIdx.x;
    int lane = threadIdx.x & 63;
    int col = blockIdx.y * 64 + lane;
    int w = threadIdx.x >> 6;
    const float* a = A + (size_t)row * K;
    float acc = 0.f;
#pragma unroll 4
    for (int k = w; k < K; k += 4) acc += a[k] * W[(size_t)k * N + col];
    red[w][lane] = acc;
    __syncthreads();
    if (w == 0) {
        float v = red[0][lane] + red[1][lane] + red[2][lane] + red[3][lane] + bias[col];
        if (ACT) v = softplus_f(v);
        C[(size_t)row * N + col] = v;
    }
}

// pred[g, 0:2] = P[g,:256] @ hw3 + hb3 ; one block per graph
__global__ __launch_bounds__(256) void k_pred(const float* __restrict__ P,
                                              const float* __restrict__ hw3,
                                              const float* __restrict__ hb3,
                                              float* __restrict__ out) {
    __shared__ float red[2][4];
    int g = blockIdx.x;
    int t = threadIdx.x;
    float q = P[(size_t)g * 256 + t];
    float r0 = q * hw3[t * 2 + 0];
    float r1 = q * hw3[t * 2 + 1];
#pragma unroll
    for (int off = 32; off > 0; off >>= 1) {
        r0 += __shfl_down(r0, off);
        r1 += __shfl_down(r1, off);
    }
    if ((t & 63) == 0) { red[0][t >> 6] = r0; red[1][t >> 6] = r1; }
    __syncthreads();
    if (t == 0) {
        out[(size_t)NGRAPH * 512 + g * 2 + 0] = red[0][0] + red[0][1] + red[0][2] + red[0][3] + hb3[0];
        out[(size_t)NGRAPH * 512 + g * 2 + 1] = red[1][0] + red[1][1] + red[1][2] + red[1][3] + hb3[1];
    }
}

// ---------------- launch ----------------
extern "C" void kernel_launch(void* const* d_in, const int* in_sizes, int n_in,
                              void* d_out, int out_size, void* d_ws, size_t ws_size,
                              hipStream_t stream) {
    const int* x      = (const int*)d_in[0];
    const int* ei     = (const int*)d_in[1];
    const int* ea     = (const int*)d_in[2];
    const int* batch  = (const int*)d_in[3];
    const float* x_emb1 = (const float*)d_in[4];
    const float* x_emb2 = (const float*)d_in[5];
    const float* e1_emb = (const float*)d_in[6];
    const float* e2_emb = (const float*)d_in[7];
    const float* w1   = (const float*)d_in[8];
    const float* b1   = (const float*)d_in[9];
    const float* w2   = (const float*)d_in[10];
    const float* b2   = (const float*)d_in[11];
    const float* bn_g = (const float*)d_in[12];
    const float* bn_b = (const float*)d_in[13];
    const float* feat_w = (const float*)d_in[14];
    const float* feat_b = (const float*)d_in[15];
    const float* hw1  = (const float*)d_in[16];
    const float* hb1  = (const float*)d_in[17];
    const float* hw2  = (const float*)d_in[18];
    const float* hb2  = (const float*)d_in[19];
    const float* hw3  = (const float*)d_in[20];
    const float* hb3  = (const float*)d_in[21];
    float* out = (float*)d_out;

    char* p = (char*)d_ws;
    auto alloc = [&](size_t bytes) -> char* {
        char* r = p;
        p += ((bytes + 255) / 256) * 256;
        return r;
    };
    float* h_a   = (float*)alloc((size_t)NODES * EMB * 4);
    float* h_b   = (float*)alloc((size_t)NODES * EMB * 4);
    u16* aggB    = (u16*)alloc((size_t)NODES * KP1 * 2);
    u16* T       = (u16*)alloc((size_t)NODES * NP1 * 2);
    u16* w1bT    = (u16*)alloc((size_t)LAYERS * NP1 * KP1 * 2);
    u16* w2bT    = (u16*)alloc((size_t)LAYERS * KP1 * NP1 * 2);
    float* comb  = (float*)alloc((size_t)LAYERS * 18 * EMB * 4);
    int* row_off = (int*)alloc((NODES + 1) * 4);
    int* cursor  = (int*)alloc(NODES * 4);
    int* packed  = (int*)alloc((size_t)ETOT * 4);
    float* stats = (float*)alloc(2 * 304 * 4);
    int* goff    = (int*)alloc((NGRAPH + 1) * 4);
    float* hg    = (float*)alloc((size_t)NGRAPH * EMB * 4);
    float* pb1   = (float*)alloc((size_t)NGRAPH * 256 * 4);
    float* pb2   = (float*)alloc((size_t)NGRAPH * 256 * 4);
    if ((size_t)(p - (char*)d_ws) > ws_size) return;  // workspace too small

    // CSR build (once; shared across layers)
    hipMemsetAsync(cursor, 0, NODES * 4, stream);
    k_count<<<(ETOT + 255) / 256, 256, 0, stream>>>(ei, cursor);
    k_scan<<<1, 1024, 0, stream>>>(cursor, row_off, cursor);
    k_fill<<<(ETOT + 255) / 256, 256, 0, stream>>>(ei, ea, cursor, packed);

    k_embed<<<(NODES * EMB + 255) / 256, 256, 0, stream>>>(x, x_emb1, x_emb2, h_a);
    k_comb<<<(LAYERS * 18 * EMB + 255) / 256, 256, 0, stream>>>(e1_emb, e2_emb, comb);
    k_convw1<<<(LAYERS * NP1 * KP1 + 255) / 256, 256, 0, stream>>>(w1, w1bT);
    k_convw2<<<(LAYERS * KP1 * NP1 + 255) / 256, 256, 0, stream>>>(w2, w2bT);
    k_goff<<<1, 128, 0, stream>>>(batch, goff);

    for (int l = 0; l < LAYERS; ++l) {
        const float* h_in = (l & 1) ? h_b : h_a;
        float* h_out      = (l & 1) ? h_a : h_b;
        k_aggregate<<<NODES / 4, 256, 0, stream>>>(h_in, row_off, packed,
                                                   comb + (size_t)l * 18 * EMB, aggB);
        k_gemm<0><<<dim3(NODES / 64, NP1 / 64), 256, 0, stream>>>(
            aggB, w1bT + (size_t)l * NP1 * KP1, b1 + l * 600, 600, T, NP1, KP1);
        k_gemm<1><<<dim3(NODES / 64, KP1 / 64), 256, 0, stream>>>(
            T, w2bT + (size_t)l * KP1 * NP1, b2 + l * EMB, EMB, h_out, 0, NP1);
        hipMemsetAsync(stats, 0, 2 * 304 * 4, stream);
        k_bnstats<<<NODES / 100, 256, 0, stream>>>(h_out, stats, stats + 304);
        k_bnapply<<<(NODES * EMB + 255) / 256, 256, 0, stream>>>(
            h_out, stats, stats + 304, bn_g + l * EMB, bn_b + l * EMB,
            (l < LAYERS - 1) ? 1 : 0);
    }

    const float* h_fin = h_b;  // layer 4 wrote h_b
    k_pool<<<dim3(NGRAPH, 5), 256, 0, stream>>>(h_fin, goff, hg);
    k_small_mm<0><<<dim3(NGRAPH, 8), 256, 0, stream>>>(hg, feat_w, feat_b, out, 512, EMB);
    k_small_mm<1><<<dim3(NGRAPH, 4), 256, 0, stream>>>(out, hw1, hb1, pb1, 256, 512);
    k_small_mm<1><<<dim3(NGRAPH, 4), 256, 0, stream>>>(pb1, hw2, hb2, pb2, 256, 256);
    k_pred<<<NGRAPH, 256, 0, stream>>>(pb2, hw3, hb3, out);
}

// Round 4
// 671.825 us; speedup vs baseline: 2.0976x; 1.6446x over previous
//
#include <hip/hip_runtime.h>

#define NODES 16000
#define EDGES 256000
#define ETOT  272000   // EDGES + NODES self-loops
#define EMB   300
#define KP1   320      // padded EMB (mult of 32)
#define NP1   640      // padded 2*EMB (mult of 64)
#define NGRAPH 64
#define LAYERS 5
#define INV_N (1.0f / 16000.0f)

typedef unsigned short u16;
typedef __bf16 bf16_t;
typedef bf16_t bf16x8 __attribute__((ext_vector_type(8)));
typedef float f32x4 __attribute__((ext_vector_type(4)));

__device__ inline u16 f2bf(float f) {
    bf16_t b = (bf16_t)f;
    return __builtin_bit_cast(u16, b);
}

__device__ inline float softplus_f(float x) {
    return fmaxf(x, 0.f) + log1pf(expf(-fabsf(x)));
}

// BN affine from raw moments: y = x*s + t
__device__ inline void bn_coef(const float* __restrict__ ssum, const float* __restrict__ ssq,
                               const float* __restrict__ g, const float* __restrict__ b,
                               int c, float& s, float& t) {
    float mean = ssum[c] * INV_N;
    float var = ssq[c] * INV_N - mean * mean;
    float rstd = rsqrtf(var + 1e-5f);
    s = rstd * g[c];
    t = b[c] - mean * s;
}

// ---------------- CSR build ----------------
__global__ void k_count(const int* __restrict__ ei, int* __restrict__ cnt) {
    int e = blockIdx.x * 256 + threadIdx.x;
    if (e >= ETOT) return;
    int dst = (e < EDGES) ? ei[EDGES + e] : (e - EDGES);
    atomicAdd(&cnt[dst], 1);
}

__global__ void k_scan(const int* cnt_in, int* row_off, int* cursor) {
    __shared__ int s[1024];
    __shared__ int carry;
    int t = threadIdx.x;
    if (t == 0) { carry = 0; row_off[0] = 0; }
    __syncthreads();
    for (int base = 0; base < NODES; base += 1024) {
        int idx = base + t;
        int v = (idx < NODES) ? cnt_in[idx] : 0;
        s[t] = v;
        __syncthreads();
        for (int off = 1; off < 1024; off <<= 1) {
            int add = (t >= off) ? s[t - off] : 0;
            __syncthreads();
            s[t] += add;
            __syncthreads();
        }
        int incl = s[t];
        int c = carry;
        if (idx < NODES) { row_off[idx + 1] = c + incl; cursor[idx] = c + incl - v; }
        __syncthreads();
        if (t == 1023) carry = c + incl;
        __syncthreads();
    }
}

__global__ void k_fill(const int* __restrict__ ei, const int* __restrict__ ea,
                       int* __restrict__ cursor, int* __restrict__ packed) {
    int e = blockIdx.x * 256 + threadIdx.x;
    if (e >= ETOT) return;
    int src, dst, c;
    if (e < EDGES) {
        src = ei[e]; dst = ei[EDGES + e];
        c = ea[e * 2] * 3 + ea[e * 2 + 1];
    } else {
        src = dst = e - EDGES; c = 15;  // self-loop attr (5,0) -> 5*3+0
    }
    int pos = atomicAdd(&cursor[dst], 1);
    packed[pos] = src | (c << 20);
}

// ---------------- setup ----------------
__global__ void k_embed(const int* __restrict__ x, const float* __restrict__ e1,
                        const float* __restrict__ e2, float* __restrict__ h) {
    int id = blockIdx.x * 256 + threadIdx.x;
    if (id >= NODES * EMB) return;
    int i = id / EMB, f = id - i * EMB;
    h[id] = e1[x[2 * i] * EMB + f] + e2[x[2 * i + 1] * EMB + f];
}

__global__ void k_comb(const float* __restrict__ e1, const float* __restrict__ e2,
                       float* __restrict__ comb) {
    int id = blockIdx.x * 256 + threadIdx.x;
    if (id >= LAYERS * 18 * EMB) return;
    int l = id / (18 * EMB);
    int r = id - l * 18 * EMB;
    int c = r / EMB, f = r - c * EMB;
    int a = c / 3, b = c - a * 3;
    comb[id] = e1[(l * 6 + a) * EMB + f] + e2[(l * 3 + b) * EMB + f];
}

// w1bT[l][n][k] = w1[l][k][n] as bf16, zero-padded to [640][320]
__global__ void k_convw1(const float* __restrict__ w1, u16* __restrict__ w1bT) {
    int id = blockIdx.x * 256 + threadIdx.x;
    if (id >= LAYERS * NP1 * KP1) return;
    int l = id / (NP1 * KP1);
    int r = id - l * NP1 * KP1;
    int n = r / KP1, k = r - n * KP1;
    float v = (n < 600 && k < EMB) ? w1[(l * EMB + k) * 600 + n] : 0.f;
    w1bT[id] = f2bf(v);
}

// w2bT[l][n][k] = w2[l][k][n] as bf16, zero-padded to [320][640]
__global__ void k_convw2(const float* __restrict__ w2, u16* __restrict__ w2bT) {
    int id = blockIdx.x * 256 + threadIdx.x;
    if (id >= LAYERS * KP1 * NP1) return;
    int l = id / (KP1 * NP1);
    int r = id - l * KP1 * NP1;
    int n = r / NP1, k = r - n * NP1;
    float v = (n < EMB && k < 600) ? w2[(l * 600 + k) * EMB + n] : 0.f;
    w2bT[id] = f2bf(v);
}

// ---------------- aggregation: one wave per node, fused BN+relu of previous layer ----
__global__ __launch_bounds__(256) void k_aggregate(
    const float* __restrict__ h, const int* __restrict__ row_off,
    const int* __restrict__ packed, const float* __restrict__ comb,
    u16* __restrict__ aggB,
    const float* __restrict__ ssum, const float* __restrict__ ssq,
    const float* __restrict__ bng, const float* __restrict__ bnb, int use_bn) {
    int node = blockIdx.x * 4 + (threadIdx.x >> 6);
    int lane = threadIdx.x & 63;
    int s = row_off[node], e = row_off[node + 1];
    int f4 = 256 + lane;
    bool has4 = f4 < EMB;
    float s0 = 1.f, t0 = 0.f, s1 = 1.f, t1 = 0.f, s2 = 1.f, t2 = 0.f,
          s3 = 1.f, t3 = 0.f, s4 = 1.f, t4 = 0.f;
    if (use_bn) {
        bn_coef(ssum, ssq, bng, bnb, lane,       s0, t0);
        bn_coef(ssum, ssq, bng, bnb, lane + 64,  s1, t1);
        bn_coef(ssum, ssq, bng, bnb, lane + 128, s2, t2);
        bn_coef(ssum, ssq, bng, bnb, lane + 192, s3, t3);
        if (has4) bn_coef(ssum, ssq, bng, bnb, f4, s4, t4);
    }
    float a0 = 0, a1 = 0, a2 = 0, a3 = 0, a4 = 0;
    if (use_bn) {
        for (int p = s; p < e; ++p) {
            int pk = packed[p];
            int src = pk & 0xFFFFF;
            int c = pk >> 20;
            const float* hr = h + (size_t)src * EMB;
            const float* cr = comb + c * EMB;
            a0 += fmaxf(hr[lane]       * s0 + t0, 0.f) + cr[lane];
            a1 += fmaxf(hr[lane + 64]  * s1 + t1, 0.f) + cr[lane + 64];
            a2 += fmaxf(hr[lane + 128] * s2 + t2, 0.f) + cr[lane + 128];
            a3 += fmaxf(hr[lane + 192] * s3 + t3, 0.f) + cr[lane + 192];
            if (has4) a4 += fmaxf(hr[f4] * s4 + t4, 0.f) + cr[f4];
        }
    } else {
        for (int p = s; p < e; ++p) {
            int pk = packed[p];
            int src = pk & 0xFFFFF;
            int c = pk >> 20;
            const float* hr = h + (size_t)src * EMB;
            const float* cr = comb + c * EMB;
            a0 += hr[lane]       + cr[lane];
            a1 += hr[lane + 64]  + cr[lane + 64];
            a2 += hr[lane + 128] + cr[lane + 128];
            a3 += hr[lane + 192] + cr[lane + 192];
            if (has4) a4 += hr[f4] + cr[f4];
        }
    }
    u16* o = aggB + (size_t)node * KP1;
    o[lane]       = f2bf(a0);
    o[lane + 64]  = f2bf(a1);
    o[lane + 128] = f2bf(a2);
    o[lane + 192] = f2bf(a3);
    o[lane + 256] = has4 ? f2bf(a4) : (u16)0;
}

// ---------------- bf16 MFMA GEMM: C[M,N] = A[M,K] * Bt[N,K]^T ----------------
// MODE 0: +bias, relu, store bf16 to Cv (ldc stride)
// MODE 1: +bias, store f32 to Cv (stride 300, cols < 300) + fused column stats
template <int MODE>
__global__ __launch_bounds__(256) void k_gemm(
    const u16* __restrict__ A, const u16* __restrict__ Bt,
    const float* __restrict__ bias, int nbias,
    void* __restrict__ Cv, int ldc, int K,
    float* __restrict__ ssum, float* __restrict__ ssq) {
    __shared__ __align__(16) u16 Al[64 * 40];
    __shared__ __align__(16) u16 Bl[64 * 40];
    __shared__ float rs[4][64];
    __shared__ float rq[4][64];
    int t = threadIdx.x;
    int m0 = blockIdx.x * 64, n0 = blockIdx.y * 64;
    int lane = t & 63, w = t >> 6;
    int srow = t >> 2, schunk = (t & 3) * 8;
    const u16* Ag = A + (size_t)(m0 + srow) * K + schunk;
    const u16* Bg = Bt + (size_t)(n0 + srow) * K + schunk;
    f32x4 acc[4];
#pragma unroll
    for (int i = 0; i < 4; i++) acc[i] = (f32x4){0.f, 0.f, 0.f, 0.f};
    int arow = w * 16 + (lane & 15);
    int k0 = (lane >> 4) * 8;
    for (int kt = 0; kt < K; kt += 32) {
        uint4 av = *reinterpret_cast<const uint4*>(Ag + kt);
        uint4 bv = *reinterpret_cast<const uint4*>(Bg + kt);
        __syncthreads();
        *reinterpret_cast<uint4*>(&Al[srow * 40 + schunk]) = av;
        *reinterpret_cast<uint4*>(&Bl[srow * 40 + schunk]) = bv;
        __syncthreads();
        bf16x8 af = *reinterpret_cast<const bf16x8*>(&Al[arow * 40 + k0]);
#pragma unroll
        for (int cb = 0; cb < 4; ++cb) {
            bf16x8 bf = *reinterpret_cast<const bf16x8*>(&Bl[(cb * 16 + (lane & 15)) * 40 + k0]);
            acc[cb] = __builtin_amdgcn_mfma_f32_16x16x32_bf16(af, bf, acc[cb], 0, 0, 0);
        }
    }
    int rbase = m0 + w * 16 + ((lane >> 4) * 4);
    int cl = lane & 15;
#pragma unroll
    for (int cb = 0; cb < 4; ++cb) {
        int col = n0 + cb * 16 + cl;
        float bv = (col < nbias) ? bias[col] : 0.f;
        float cs = 0.f, cq = 0.f;
#pragma unroll
        for (int j = 0; j < 4; ++j) {
            float v = acc[cb][j] + bv;
            int row = rbase + j;
            if (MODE == 0) {
                v = fmaxf(v, 0.f);
                ((u16*)Cv)[(size_t)row * ldc + col] = f2bf(v);
            } else {
                if (col < EMB) ((float*)Cv)[(size_t)row * EMB + col] = v;
                cs += v;
                cq += v * v;
            }
        }
        if (MODE == 1) {
            // reduce across the 4 lane-groups holding this column (lanes differ in bits 4,5)
            cs += __shfl_xor(cs, 16); cs += __shfl_xor(cs, 32);
            cq += __shfl_xor(cq, 16); cq += __shfl_xor(cq, 32);
            if ((lane >> 4) == 0) { rs[w][cb * 16 + cl] = cs; rq[w][cb * 16 + cl] = cq; }
        }
    }
    if (MODE == 1) {
        __syncthreads();
        if (t < 64) {
            int col = n0 + t;
            if (col < EMB) {
                float S = rs[0][t] + rs[1][t] + rs[2][t] + rs[3][t];
                float Q = rq[0][t] + rq[1][t] + rq[2][t] + rq[3][t];
                atomicAdd(&ssum[col], S);
                atomicAdd(&ssq[col], Q);
            }
        }
    }
}

// ---------------- tail: graph offsets, pool (fused final BN), head GEMMs -------
__global__ void k_goff(const int* __restrict__ batch, int* __restrict__ goff) {
    int t = threadIdx.x;
    if (t > NGRAPH) return;
    int lo = 0, hi = NODES;
    while (lo < hi) { int mid = (lo + hi) >> 1; if (batch[mid] < t) lo = mid + 1; else hi = mid; }
    goff[t] = lo;
}

// grid (NGRAPH, 5): block = 4 waves x 64 lanes; wave w sums rows s+w, s+w+4, ...
// h holds PRE-BN layer-4 output; apply y = x*s + t after the mean (affine commutes).
__global__ __launch_bounds__(256) void k_pool(const float* __restrict__ h,
                                              const int* __restrict__ goff,
                                              const float* __restrict__ ssum,
                                              const float* __restrict__ ssq,
                                              const float* __restrict__ bng,
                                              const float* __restrict__ bnb,
                                              float* __restrict__ hg) {
    __shared__ float red[4][64];
    int g = blockIdx.x;
    int col = blockIdx.y * 64 + (threadIdx.x & 63);
    int w = threadIdx.x >> 6;
    int s = goff[g], e = goff[g + 1];
    float a = 0.f;
    bool ok = col < EMB;
    if (ok) {
        for (int r = s + w; r < e; r += 4) a += h[(size_t)r * EMB + col];
    }
    red[w][threadIdx.x & 63] = a;
    __syncthreads();
    if (w == 0 && ok) {
        float sc, tc;
        bn_coef(ssum, ssq, bng, bnb, col, sc, tc);
        float v = red[0][threadIdx.x] + red[1][threadIdx.x] +
                  red[2][threadIdx.x] + red[3][threadIdx.x];
        float inv = (e > s) ? 1.0f / (float)(e - s) : 0.f;
        hg[(size_t)g * EMB + col] = (v * inv) * sc + tc;
    }
}

// C[row, col] = act(A[row,:K] @ W[:K, col] + b[col]); grid (M, N/64), block 256.
template <int ACT>  // 0: none, 1: softplus
__global__ __launch_bounds__(256) void k_small_mm(
    const float* __restrict__ A, const float* __restrict__ W,
    const float* __restrict__ bias, float* __restrict__ C, int N, int K) {
    __shared__ float red[4][64];
    int row = blockIdx.x;
    int lane = threadIdx.x & 63;
    int col = blockIdx.y * 64 + lane;
    int w = threadIdx.x >> 6;
    const float* a = A + (size_t)row * K;
    float acc = 0.f;
#pragma unroll 4
    for (int k = w; k < K; k += 4) acc += a[k] * W[(size_t)k * N + col];
    red[w][lane] = acc;
    __syncthreads();
    if (w == 0) {
        float v = red[0][lane] + red[1][lane] + red[2][lane] + red[3][lane] + bias[col];
        if (ACT) v = softplus_f(v);
        C[(size_t)row * N + col] = v;
    }
}

// pred[g, 0:2] = P[g,:256] @ hw3 + hb3 ; one block per graph
__global__ __launch_bounds__(256) void k_pred(const float* __restrict__ P,
                                              const float* __restrict__ hw3,
                                              const float* __restrict__ hb3,
                                              float* __restrict__ out) {
    __shared__ float red[2][4];
    int g = blockIdx.x;
    int t = threadIdx.x;
    float q = P[(size_t)g * 256 + t];
    float r0 = q * hw3[t * 2 + 0];
    float r1 = q * hw3[t * 2 + 1];
#pragma unroll
    for (int off = 32; off > 0; off >>= 1) {
        r0 += __shfl_down(r0, off);
        r1 += __shfl_down(r1, off);
    }
    if ((t & 63) == 0) { red[0][t >> 6] = r0; red[1][t >> 6] = r1; }
    __syncthreads();
    if (t == 0) {
        out[(size_t)NGRAPH * 512 + g * 2 + 0] = red[0][0] + red[0][1] + red[0][2] + red[0][3] + hb3[0];
        out[(size_t)NGRAPH * 512 + g * 2 + 1] = red[1][0] + red[1][1] + red[1][2] + red[1][3] + hb3[1];
    }
}

// ---------------- launch ----------------
extern "C" void kernel_launch(void* const* d_in, const int* in_sizes, int n_in,
                              void* d_out, int out_size, void* d_ws, size_t ws_size,
                              hipStream_t stream) {
    const int* x      = (const int*)d_in[0];
    const int* ei     = (const int*)d_in[1];
    const int* ea     = (const int*)d_in[2];
    const int* batch  = (const int*)d_in[3];
    const float* x_emb1 = (const float*)d_in[4];
    const float* x_emb2 = (const float*)d_in[5];
    const float* e1_emb = (const float*)d_in[6];
    const float* e2_emb = (const float*)d_in[7];
    const float* w1   = (const float*)d_in[8];
    const float* b1   = (const float*)d_in[9];
    const float* w2   = (const float*)d_in[10];
    const float* b2   = (const float*)d_in[11];
    const float* bn_g = (const float*)d_in[12];
    const float* bn_b = (const float*)d_in[13];
    const float* feat_w = (const float*)d_in[14];
    const float* feat_b = (const float*)d_in[15];
    const float* hw1  = (const float*)d_in[16];
    const float* hb1  = (const float*)d_in[17];
    const float* hw2  = (const float*)d_in[18];
    const float* hb2  = (const float*)d_in[19];
    const float* hw3  = (const float*)d_in[20];
    const float* hb3  = (const float*)d_in[21];
    float* out = (float*)d_out;

    char* p = (char*)d_ws;
    auto alloc = [&](size_t bytes) -> char* {
        char* r = p;
        p += ((bytes + 255) / 256) * 256;
        return r;
    };
    float* h_a   = (float*)alloc((size_t)NODES * EMB * 4);
    float* h_b   = (float*)alloc((size_t)NODES * EMB * 4);
    u16* aggB    = (u16*)alloc((size_t)NODES * KP1 * 2);
    u16* T       = (u16*)alloc((size_t)NODES * NP1 * 2);
    u16* w1bT    = (u16*)alloc((size_t)LAYERS * NP1 * KP1 * 2);
    u16* w2bT    = (u16*)alloc((size_t)LAYERS * KP1 * NP1 * 2);
    float* comb  = (float*)alloc((size_t)LAYERS * 18 * EMB * 4);
    int* row_off = (int*)alloc((NODES + 1) * 4);
    int* cursor  = (int*)alloc(NODES * 4);
    int* packed  = (int*)alloc((size_t)ETOT * 4);
    float* stats = (float*)alloc(2 * 304 * 4);
    int* goff    = (int*)alloc((NGRAPH + 1) * 4);
    float* hg    = (float*)alloc((size_t)NGRAPH * EMB * 4);
    float* pb1   = (float*)alloc((size_t)NGRAPH * 256 * 4);
    float* pb2   = (float*)alloc((size_t)NGRAPH * 256 * 4);
    if ((size_t)(p - (char*)d_ws) > ws_size) return;  // workspace too small

    float* ssum = stats;
    float* ssq  = stats + 304;

    // CSR build (once; shared across layers)
    hipMemsetAsync(cursor, 0, NODES * 4, stream);
    k_count<<<(ETOT + 255) / 256, 256, 0, stream>>>(ei, cursor);
    k_scan<<<1, 1024, 0, stream>>>(cursor, row_off, cursor);
    k_fill<<<(ETOT + 255) / 256, 256, 0, stream>>>(ei, ea, cursor, packed);

    k_embed<<<(NODES * EMB + 255) / 256, 256, 0, stream>>>(x, x_emb1, x_emb2, h_a);
    k_comb<<<(LAYERS * 18 * EMB + 255) / 256, 256, 0, stream>>>(e1_emb, e2_emb, comb);
    k_convw1<<<(LAYERS * NP1 * KP1 + 255) / 256, 256, 0, stream>>>(w1, w1bT);
    k_convw2<<<(LAYERS * KP1 * NP1 + 255) / 256, 256, 0, stream>>>(w2, w2bT);
    k_goff<<<1, 128, 0, stream>>>(batch, goff);

    for (int l = 0; l < LAYERS; ++l) {
        const float* h_in = (l & 1) ? h_b : h_a;
        float* h_out      = (l & 1) ? h_a : h_b;
        // aggregate consumes h_in with the PREVIOUS layer's BN(+relu) fused (l>0)
        k_aggregate<<<NODES / 4, 256, 0, stream>>>(
            h_in, row_off, packed, comb + (size_t)l * 18 * EMB, aggB,
            ssum, ssq, bn_g + (l > 0 ? (l - 1) * EMB : 0), bn_b + (l > 0 ? (l - 1) * EMB : 0),
            l > 0 ? 1 : 0);
        k_gemm<0><<<dim3(NODES / 64, NP1 / 64), 256, 0, stream>>>(
            aggB, w1bT + (size_t)l * NP1 * KP1, b1 + l * 600, 600, T, NP1, KP1,
            nullptr, nullptr);
        hipMemsetAsync(stats, 0, 2 * 304 * 4, stream);
        k_gemm<1><<<dim3(NODES / 64, KP1 / 64), 256, 0, stream>>>(
            T, w2bT + (size_t)l * KP1 * NP1, b2 + l * EMB, EMB, h_out, 0, NP1,
            ssum, ssq);
    }

    const float* h_fin = h_b;  // layer 4 wrote h_b (pre-BN); pool applies BN affine
    k_pool<<<dim3(NGRAPH, 5), 256, 0, stream>>>(h_fin, goff, ssum, ssq,
                                                bn_g + 4 * EMB, bn_b + 4 * EMB, hg);
    k_small_mm<0><<<dim3(NGRAPH, 8), 256, 0, stream>>>(hg, feat_w, feat_b, out, 512, EMB);
    k_small_mm<1><<<dim3(NGRAPH, 4), 256, 0, stream>>>(out, hw1, hb1, pb1, 256, 512);
    k_small_mm<1><<<dim3(NGRAPH, 4), 256, 0, stream>>>(pb1, hw2, hb2, pb2, 256, 256);
    k_pred<<<NGRAPH, 256, 0, stream>>>(pb2, hw3, hb3, out);
}

// Round 5
// 574.349 us; speedup vs baseline: 2.4536x; 1.1697x over previous
//
#include <hip/hip_runtime.h>

#define NODES 16000
#define EDGES 256000
#define ETOT  272000   // EDGES + NODES self-loops
#define EMB   300
#define KP1   320      // padded EMB (mult of 32)
#define NP1   640      // padded 2*EMB (mult of 64)
#define NP2B  384      // padded rows for w2bT (3 x 128 tiles)
#define NGRAPH 64
#define LAYERS 5
#define INV_N (1.0f / 16000.0f)

typedef unsigned short u16;
typedef unsigned int u32;
typedef __bf16 bf16_t;
typedef bf16_t bf16x8 __attribute__((ext_vector_type(8)));
typedef float f32x4 __attribute__((ext_vector_type(4)));

__device__ inline u16 f2bf(float f) {
    bf16_t b = (bf16_t)f;
    return __builtin_bit_cast(u16, b);
}
__device__ inline float bf_lo(u32 u) { return __builtin_bit_cast(float, u << 16); }
__device__ inline float bf_hi(u32 u) { return __builtin_bit_cast(float, u & 0xFFFF0000u); }
__device__ inline u32 bf_pack(float lo, float hi) {
    return ((u32)f2bf(hi) << 16) | (u32)f2bf(lo);
}

__device__ inline float softplus_f(float x) {
    return fmaxf(x, 0.f) + log1pf(expf(-fabsf(x)));
}

// BN affine from raw moments: y = x*s + t
__device__ inline void bn_coef(const float* __restrict__ ssum, const float* __restrict__ ssq,
                               const float* __restrict__ g, const float* __restrict__ b,
                               int c, float& s, float& t) {
    float mean = ssum[c] * INV_N;
    float var = ssq[c] * INV_N - mean * mean;
    float rstd = rsqrtf(var + 1e-5f);
    s = rstd * g[c];
    t = b[c] - mean * s;
}

// ---------------- CSR build ----------------
__global__ void k_count(const int* __restrict__ ei, int* __restrict__ cnt) {
    int e = blockIdx.x * 256 + threadIdx.x;
    if (e >= ETOT) return;
    int dst = (e < EDGES) ? ei[EDGES + e] : (e - EDGES);
    atomicAdd(&cnt[dst], 1);
}

__global__ void k_scan(const int* cnt_in, int* row_off, int* cursor) {
    __shared__ int s[1024];
    __shared__ int carry;
    int t = threadIdx.x;
    if (t == 0) { carry = 0; row_off[0] = 0; }
    __syncthreads();
    for (int base = 0; base < NODES; base += 1024) {
        int idx = base + t;
        int v = (idx < NODES) ? cnt_in[idx] : 0;
        s[t] = v;
        __syncthreads();
        for (int off = 1; off < 1024; off <<= 1) {
            int add = (t >= off) ? s[t - off] : 0;
            __syncthreads();
            s[t] += add;
            __syncthreads();
        }
        int incl = s[t];
        int c = carry;
        if (idx < NODES) { row_off[idx + 1] = c + incl; cursor[idx] = c + incl - v; }
        __syncthreads();
        if (t == 1023) carry = c + incl;
        __syncthreads();
    }
}

__global__ void k_fill(const int* __restrict__ ei, const int* __restrict__ ea,
                       int* __restrict__ cursor, int* __restrict__ packed) {
    int e = blockIdx.x * 256 + threadIdx.x;
    if (e >= ETOT) return;
    int src, dst, c;
    if (e < EDGES) {
        src = ei[e]; dst = ei[EDGES + e];
        c = ea[e * 2] * 3 + ea[e * 2 + 1];
    } else {
        src = dst = e - EDGES; c = 15;  // self-loop attr (5,0) -> 5*3+0
    }
    int pos = atomicAdd(&cursor[dst], 1);
    packed[pos] = src | (c << 20);
}

// ---------------- setup ----------------
__global__ void k_embed(const int* __restrict__ x, const float* __restrict__ e1,
                        const float* __restrict__ e2, u16* __restrict__ h) {
    int id = blockIdx.x * 256 + threadIdx.x;
    if (id >= NODES * EMB) return;
    int i = id / EMB, f = id - i * EMB;
    h[id] = f2bf(e1[x[2 * i] * EMB + f] + e2[x[2 * i + 1] * EMB + f]);
}

__global__ void k_comb(const float* __restrict__ e1, const float* __restrict__ e2,
                       u16* __restrict__ comb) {
    int id = blockIdx.x * 256 + threadIdx.x;
    if (id >= LAYERS * 18 * EMB) return;
    int l = id / (18 * EMB);
    int r = id - l * 18 * EMB;
    int c = r / EMB, f = r - c * EMB;
    int a = c / 3, b = c - a * 3;
    comb[id] = f2bf(e1[(l * 6 + a) * EMB + f] + e2[(l * 3 + b) * EMB + f]);
}

// w1bT[l][n][k] = w1[l][k][n] as bf16, zero-padded to [640][320]
__global__ void k_convw1(const float* __restrict__ w1, u16* __restrict__ w1bT) {
    int id = blockIdx.x * 256 + threadIdx.x;
    if (id >= LAYERS * NP1 * KP1) return;
    int l = id / (NP1 * KP1);
    int r = id - l * NP1 * KP1;
    int n = r / KP1, k = r - n * KP1;
    float v = (n < 600 && k < EMB) ? w1[(l * EMB + k) * 600 + n] : 0.f;
    w1bT[id] = f2bf(v);
}

// w2bT[l][n][k] = w2[l][k][n] as bf16, zero-padded to [384][640]
__global__ void k_convw2(const float* __restrict__ w2, u16* __restrict__ w2bT) {
    int id = blockIdx.x * 256 + threadIdx.x;
    if (id >= LAYERS * NP2B * NP1) return;
    int l = id / (NP2B * NP1);
    int r = id - l * NP2B * NP1;
    int n = r / NP1, k = r - n * NP1;
    float v = (n < EMB && k < 600) ? w2[(l * 600 + k) * EMB + n] : 0.f;
    w2bT[id] = f2bf(v);
}

// ---------------- aggregation: one wave per node, bf16 h/comb, fused BN+relu ----
// Each lane owns feature pairs {2l,2l+1}, {128+2l,128+2l+1}, {256+2l,256+2l+1 (l<22)}.
__global__ __launch_bounds__(256) void k_aggregate(
    const u16* __restrict__ h, const int* __restrict__ row_off,
    const int* __restrict__ packed, const u16* __restrict__ comb,
    u16* __restrict__ aggB,
    const float* __restrict__ ssum, const float* __restrict__ ssq,
    const float* __restrict__ bng, const float* __restrict__ bnb, int use_bn) {
    int node = blockIdx.x * 4 + (threadIdx.x >> 6);
    int lane = threadIdx.x & 63;
    int s = row_off[node], e = row_off[node + 1];
    bool has2 = lane < 22;  // features 256..299 = 22 uint pairs
    const u32* hu = (const u32*)h;
    const u32* cu = (const u32*)comb;
    float s0l = 1.f, t0l = 0.f, s0h = 1.f, t0h = 0.f;
    float s1l = 1.f, t1l = 0.f, s1h = 1.f, t1h = 0.f;
    float s2l = 1.f, t2l = 0.f, s2h = 1.f, t2h = 0.f;
    if (use_bn) {
        bn_coef(ssum, ssq, bng, bnb, 2 * lane,           s0l, t0l);
        bn_coef(ssum, ssq, bng, bnb, 2 * lane + 1,       s0h, t0h);
        bn_coef(ssum, ssq, bng, bnb, 128 + 2 * lane,     s1l, t1l);
        bn_coef(ssum, ssq, bng, bnb, 128 + 2 * lane + 1, s1h, t1h);
        if (has2) {
            bn_coef(ssum, ssq, bng, bnb, 256 + 2 * lane,     s2l, t2l);
            bn_coef(ssum, ssq, bng, bnb, 256 + 2 * lane + 1, s2h, t2h);
        }
    }
    float a0l = 0, a0h = 0, a1l = 0, a1h = 0, a2l = 0, a2h = 0;
    if (use_bn) {
        for (int p = s; p < e; ++p) {
            int pk = packed[p];
            const u32* hr = hu + (size_t)(pk & 0xFFFFF) * 150;
            const u32* cr = cu + (pk >> 20) * 150;
            u32 u0 = hr[lane], u1 = hr[64 + lane];
            u32 v0 = cr[lane], v1 = cr[64 + lane];
            u32 u2 = 0, v2 = 0;
            if (has2) { u2 = hr[128 + lane]; v2 = cr[128 + lane]; }
            a0l += fmaxf(bf_lo(u0) * s0l + t0l, 0.f) + bf_lo(v0);
            a0h += fmaxf(bf_hi(u0) * s0h + t0h, 0.f) + bf_hi(v0);
            a1l += fmaxf(bf_lo(u1) * s1l + t1l, 0.f) + bf_lo(v1);
            a1h += fmaxf(bf_hi(u1) * s1h + t1h, 0.f) + bf_hi(v1);
            a2l += fmaxf(bf_lo(u2) * s2l + t2l, 0.f) + bf_lo(v2);
            a2h += fmaxf(bf_hi(u2) * s2h + t2h, 0.f) + bf_hi(v2);
        }
    } else {
        for (int p = s; p < e; ++p) {
            int pk = packed[p];
            const u32* hr = hu + (size_t)(pk & 0xFFFFF) * 150;
            const u32* cr = cu + (pk >> 20) * 150;
            u32 u0 = hr[lane], u1 = hr[64 + lane];
            u32 v0 = cr[lane], v1 = cr[64 + lane];
            u32 u2 = 0, v2 = 0;
            if (has2) { u2 = hr[128 + lane]; v2 = cr[128 + lane]; }
            a0l += bf_lo(u0) + bf_lo(v0);
            a0h += bf_hi(u0) + bf_hi(v0);
            a1l += bf_lo(u1) + bf_lo(v1);
            a1h += bf_hi(u1) + bf_hi(v1);
            a2l += bf_lo(u2) + bf_lo(v2);
            a2h += bf_hi(u2) + bf_hi(v2);
        }
    }
    u32* o = (u32*)(aggB + (size_t)node * KP1);
    o[lane] = bf_pack(a0l, a0h);
    o[64 + lane] = bf_pack(a1l, a1h);
    if (lane < 32) o[128 + lane] = has2 ? bf_pack(a2l, a2h) : 0u;  // pads 300..319 = 0
}

// ---------------- bf16 MFMA GEMM, 128x128 tile: C = A[M,K] * Bt[N,K]^T ----------
// 4 waves in 2x2; each wave computes 64x64 (4x4 fragments of 16x16x32).
// MODE 0: +bias, relu, bf16 store (ldc stride)
// MODE 1: +bias, bf16 store (EMB stride, col<300) + fused column stats
template <int MODE>
__global__ __launch_bounds__(256) void k_gemm(
    const u16* __restrict__ A, const u16* __restrict__ Bt,
    const float* __restrict__ bias, int nbias,
    u16* __restrict__ Cv, int ldc, int K,
    float* __restrict__ ssum, float* __restrict__ ssq) {
    __shared__ __align__(16) u16 Al[128 * 40];
    __shared__ __align__(16) u16 Bl[128 * 40];
    __shared__ float rs[2][128];
    __shared__ float rq[2][128];
    int t = threadIdx.x;
    int m0 = blockIdx.x * 128, n0 = blockIdx.y * 128;
    int lane = t & 63, w = t >> 6;
    int wr = w >> 1, wc = w & 1;
    int srow = t >> 2, sch = (t & 3) * 8;
    const u16* Ag0 = A + (size_t)(m0 + srow) * K + sch;
    const u16* Ag1 = Ag0 + (size_t)64 * K;
    const u16* Bg0 = Bt + (size_t)(n0 + srow) * K + sch;
    const u16* Bg1 = Bg0 + (size_t)64 * K;
    f32x4 acc[4][4];
#pragma unroll
    for (int i = 0; i < 4; i++)
#pragma unroll
        for (int j = 0; j < 4; j++) acc[i][j] = (f32x4){0.f, 0.f, 0.f, 0.f};
    int fr = lane & 15;
    int k0 = (lane >> 4) * 8;
    int abase = (wr * 64 + fr) * 40 + k0;
    int bbase = (wc * 64 + fr) * 40 + k0;
    for (int kt = 0; kt < K; kt += 32) {
        uint4 a0 = *reinterpret_cast<const uint4*>(Ag0 + kt);
        uint4 a1 = *reinterpret_cast<const uint4*>(Ag1 + kt);
        uint4 b0 = *reinterpret_cast<const uint4*>(Bg0 + kt);
        uint4 b1 = *reinterpret_cast<const uint4*>(Bg1 + kt);
        __syncthreads();
        *reinterpret_cast<uint4*>(&Al[srow * 40 + sch]) = a0;
        *reinterpret_cast<uint4*>(&Al[(srow + 64) * 40 + sch]) = a1;
        *reinterpret_cast<uint4*>(&Bl[srow * 40 + sch]) = b0;
        *reinterpret_cast<uint4*>(&Bl[(srow + 64) * 40 + sch]) = b1;
        __syncthreads();
        bf16x8 af[4], bfv[4];
#pragma unroll
        for (int f = 0; f < 4; ++f) {
            af[f]  = *reinterpret_cast<const bf16x8*>(&Al[abase + f * 16 * 40]);
            bfv[f] = *reinterpret_cast<const bf16x8*>(&Bl[bbase + f * 16 * 40]);
        }
#pragma unroll
        for (int fm = 0; fm < 4; ++fm)
#pragma unroll
            for (int fn = 0; fn < 4; ++fn)
                acc[fm][fn] = __builtin_amdgcn_mfma_f32_16x16x32_bf16(
                    af[fm], bfv[fn], acc[fm][fn], 0, 0, 0);
    }
    int rg = lane >> 4;
    if (MODE == 0) {
#pragma unroll
        for (int fn = 0; fn < 4; ++fn) {
            int col = n0 + wc * 64 + fn * 16 + fr;
            float bv = (col < nbias) ? bias[col] : 0.f;
#pragma unroll
            for (int fm = 0; fm < 4; ++fm) {
                int rb = m0 + wr * 64 + fm * 16 + rg * 4;
#pragma unroll
                for (int j = 0; j < 4; ++j) {
                    float v = fmaxf(acc[fm][fn][j] + bv, 0.f);
                    Cv[(size_t)(rb + j) * ldc + col] = f2bf(v);
                }
            }
        }
    } else {
#pragma unroll
        for (int fn = 0; fn < 4; ++fn) {
            int col = n0 + wc * 64 + fn * 16 + fr;
            float bv = (col < nbias) ? bias[col] : 0.f;
            float cs = 0.f, cq = 0.f;
#pragma unroll
            for (int fm = 0; fm < 4; ++fm) {
                int rb = m0 + wr * 64 + fm * 16 + rg * 4;
#pragma unroll
                for (int j = 0; j < 4; ++j) {
                    float v = acc[fm][fn][j] + bv;
                    if (col < EMB) Cv[(size_t)(rb + j) * EMB + col] = f2bf(v);
                    cs += v;
                    cq += v * v;
                }
            }
            cs += __shfl_xor(cs, 16); cs += __shfl_xor(cs, 32);
            cq += __shfl_xor(cq, 16); cq += __shfl_xor(cq, 32);
            if (rg == 0) {
                rs[wr][wc * 64 + fn * 16 + fr] = cs;
                rq[wr][wc * 64 + fn * 16 + fr] = cq;
            }
        }
        __syncthreads();
        if (t < 128) {
            int col = n0 + t;
            if (col < EMB) {
                atomicAdd(&ssum[col], rs[0][t] + rs[1][t]);
                atomicAdd(&ssq[col], rq[0][t] + rq[1][t]);
            }
        }
    }
}

// ---------------- tail: graph offsets, pool (fused final BN), head GEMMs -------
__global__ void k_goff(const int* __restrict__ batch, int* __restrict__ goff) {
    int t = threadIdx.x;
    if (t > NGRAPH) return;
    int lo = 0, hi = NODES;
    while (lo < hi) { int mid = (lo + hi) >> 1; if (batch[mid] < t) lo = mid + 1; else hi = mid; }
    goff[t] = lo;
}

// grid (NGRAPH, 5); h holds PRE-BN bf16 layer-4 output; affine applied post-mean.
__global__ __launch_bounds__(256) void k_pool(const u16* __restrict__ h,
                                              const int* __restrict__ goff,
                                              const float* __restrict__ ssum,
                                              const float* __restrict__ ssq,
                                              const float* __restrict__ bng,
                                              const float* __restrict__ bnb,
                                              float* __restrict__ hg) {
    __shared__ float red[4][64];
    int g = blockIdx.x;
    int col = blockIdx.y * 64 + (threadIdx.x & 63);
    int w = threadIdx.x >> 6;
    int s = goff[g], e = goff[g + 1];
    float a = 0.f;
    bool ok = col < EMB;
    if (ok) {
        for (int r = s + w; r < e; r += 4)
            a += __builtin_bit_cast(float, (u32)h[(size_t)r * EMB + col] << 16);
    }
    red[w][threadIdx.x & 63] = a;
    __syncthreads();
    if (w == 0 && ok) {
        float sc, tc;
        bn_coef(ssum, ssq, bng, bnb, col, sc, tc);
        float v = red[0][threadIdx.x] + red[1][threadIdx.x] +
                  red[2][threadIdx.x] + red[3][threadIdx.x];
        float inv = (e > s) ? 1.0f / (float)(e - s) : 0.f;
        hg[(size_t)g * EMB + col] = (v * inv) * sc + tc;
    }
}

// C[row, col] = act(A[row,:K] @ W[:K, col] + b[col]); grid (M, N/64), block 256.
template <int ACT>  // 0: none, 1: softplus
__global__ __launch_bounds__(256) void k_small_mm(
    const float* __restrict__ A, const float* __restrict__ W,
    const float* __restrict__ bias, float* __restrict__ C, int N, int K) {
    __shared__ float red[4][64];
    int row = blockIdx.x;
    int lane = threadIdx.x & 63;
    int col = blockIdx.y * 64 + lane;
    int w = threadIdx.x >> 6;
    const float* a = A + (size_t)row * K;
    float acc = 0.f;
#pragma unroll 4
    for (int k = w; k < K; k += 4) acc += a[k] * W[(size_t)k * N + col];
    red[w][lane] = acc;
    __syncthreads();
    if (w == 0) {
        float v = red[0][lane] + red[1][lane] + red[2][lane] + red[3][lane] + bias[col];
        if (ACT) v = softplus_f(v);
        C[(size_t)row * N + col] = v;
    }
}

// pred[g, 0:2] = P[g,:256] @ hw3 + hb3 ; one block per graph
__global__ __launch_bounds__(256) void k_pred(const float* __restrict__ P,
                                              const float* __restrict__ hw3,
                                              const float* __restrict__ hb3,
                                              float* __restrict__ out) {
    __shared__ float red[2][4];
    int g = blockIdx.x;
    int t = threadIdx.x;
    float q = P[(size_t)g * 256 + t];
    float r0 = q * hw3[t * 2 + 0];
    float r1 = q * hw3[t * 2 + 1];
#pragma unroll
    for (int off = 32; off > 0; off >>= 1) {
        r0 += __shfl_down(r0, off);
        r1 += __shfl_down(r1, off);
    }
    if ((t & 63) == 0) { red[0][t >> 6] = r0; red[1][t >> 6] = r1; }
    __syncthreads();
    if (t == 0) {
        out[(size_t)NGRAPH * 512 + g * 2 + 0] = red[0][0] + red[0][1] + red[0][2] + red[0][3] + hb3[0];
        out[(size_t)NGRAPH * 512 + g * 2 + 1] = red[1][0] + red[1][1] + red[1][2] + red[1][3] + hb3[1];
    }
}

// ---------------- launch ----------------
extern "C" void kernel_launch(void* const* d_in, const int* in_sizes, int n_in,
                              void* d_out, int out_size, void* d_ws, size_t ws_size,
                              hipStream_t stream) {
    const int* x      = (const int*)d_in[0];
    const int* ei     = (const int*)d_in[1];
    const int* ea     = (const int*)d_in[2];
    const int* batch  = (const int*)d_in[3];
    const float* x_emb1 = (const float*)d_in[4];
    const float* x_emb2 = (const float*)d_in[5];
    const float* e1_emb = (const float*)d_in[6];
    const float* e2_emb = (const float*)d_in[7];
    const float* w1   = (const float*)d_in[8];
    const float* b1   = (const float*)d_in[9];
    const float* w2   = (const float*)d_in[10];
    const float* b2   = (const float*)d_in[11];
    const float* bn_g = (const float*)d_in[12];
    const float* bn_b = (const float*)d_in[13];
    const float* feat_w = (const float*)d_in[14];
    const float* feat_b = (const float*)d_in[15];
    const float* hw1  = (const float*)d_in[16];
    const float* hb1  = (const float*)d_in[17];
    const float* hw2  = (const float*)d_in[18];
    const float* hb2  = (const float*)d_in[19];
    const float* hw3  = (const float*)d_in[20];
    const float* hb3  = (const float*)d_in[21];
    float* out = (float*)d_out;

    char* p = (char*)d_ws;
    auto alloc = [&](size_t bytes) -> char* {
        char* r = p;
        p += ((bytes + 255) / 256) * 256;
        return r;
    };
    u16* h_a     = (u16*)alloc((size_t)NODES * EMB * 2);
    u16* h_b     = (u16*)alloc((size_t)NODES * EMB * 2);
    u16* aggB    = (u16*)alloc((size_t)NODES * KP1 * 2);
    u16* T       = (u16*)alloc((size_t)NODES * NP1 * 2);
    u16* w1bT    = (u16*)alloc((size_t)LAYERS * NP1 * KP1 * 2);
    u16* w2bT    = (u16*)alloc((size_t)LAYERS * NP2B * NP1 * 2);
    u16* comb    = (u16*)alloc((size_t)LAYERS * 18 * EMB * 2);
    int* row_off = (int*)alloc((NODES + 1) * 4);
    int* cursor  = (int*)alloc(NODES * 4);
    int* packed  = (int*)alloc((size_t)ETOT * 4);
    float* stats = (float*)alloc(2 * 304 * 4);
    int* goff    = (int*)alloc((NGRAPH + 1) * 4);
    float* hg    = (float*)alloc((size_t)NGRAPH * EMB * 4);
    float* pb1   = (float*)alloc((size_t)NGRAPH * 256 * 4);
    float* pb2   = (float*)alloc((size_t)NGRAPH * 256 * 4);
    if ((size_t)(p - (char*)d_ws) > ws_size) return;  // workspace too small

    float* ssum = stats;
    float* ssq  = stats + 304;

    // CSR build (once; shared across layers)
    hipMemsetAsync(cursor, 0, NODES * 4, stream);
    k_count<<<(ETOT + 255) / 256, 256, 0, stream>>>(ei, cursor);
    k_scan<<<1, 1024, 0, stream>>>(cursor, row_off, cursor);
    k_fill<<<(ETOT + 255) / 256, 256, 0, stream>>>(ei, ea, cursor, packed);

    k_embed<<<(NODES * EMB + 255) / 256, 256, 0, stream>>>(x, x_emb1, x_emb2, h_a);
    k_comb<<<(LAYERS * 18 * EMB + 255) / 256, 256, 0, stream>>>(e1_emb, e2_emb, comb);
    k_convw1<<<(LAYERS * NP1 * KP1 + 255) / 256, 256, 0, stream>>>(w1, w1bT);
    k_convw2<<<(LAYERS * NP2B * NP1 + 255) / 256, 256, 0, stream>>>(w2, w2bT);
    k_goff<<<1, 128, 0, stream>>>(batch, goff);

    for (int l = 0; l < LAYERS; ++l) {
        const u16* h_in = (l & 1) ? h_b : h_a;
        u16* h_out      = (l & 1) ? h_a : h_b;
        // aggregate consumes h_in with the PREVIOUS layer's BN(+relu) fused (l>0)
        k_aggregate<<<NODES / 4, 256, 0, stream>>>(
            h_in, row_off, packed, comb + (size_t)l * 18 * EMB, aggB,
            ssum, ssq, bn_g + (l > 0 ? (l - 1) * EMB : 0), bn_b + (l > 0 ? (l - 1) * EMB : 0),
            l > 0 ? 1 : 0);
        k_gemm<0><<<dim3(NODES / 128, NP1 / 128), 256, 0, stream>>>(
            aggB, w1bT + (size_t)l * NP1 * KP1, b1 + l * 600, 600, T, NP1, KP1,
            nullptr, nullptr);
        hipMemsetAsync(stats, 0, 2 * 304 * 4, stream);
        k_gemm<1><<<dim3(NODES / 128, NP2B / 128), 256, 0, stream>>>(
            T, w2bT + (size_t)l * NP2B * NP1, b2 + l * EMB, EMB, h_out, 0, NP1,
            ssum, ssq);
    }

    const u16* h_fin = h_b;  // layer 4 wrote h_b (pre-BN); pool applies BN affine
    k_pool<<<dim3(NGRAPH, 5), 256, 0, stream>>>(h_fin, goff, ssum, ssq,
                                                bn_g + 4 * EMB, bn_b + 4 * EMB, hg);
    k_small_mm<0><<<dim3(NGRAPH, 8), 256, 0, stream>>>(hg, feat_w, feat_b, out, 512, EMB);
    k_small_mm<1><<<dim3(NGRAPH, 4), 256, 0, stream>>>(out, hw1, hb1, pb1, 256, 512);
    k_small_mm<1><<<dim3(NGRAPH, 4), 256, 0, stream>>>(pb1, hw2, hb2, pb2, 256, 256);
    k_pred<<<NGRAPH, 256, 0, stream>>>(pb2, hw3, hb3, out);
}

// Round 6
// 531.604 us; speedup vs baseline: 2.6509x; 1.0804x over previous
//
#include <hip/hip_runtime.h>

#define NODES 16000
#define EDGES 256000
#define ETOT  272000   // EDGES + NODES self-loops
#define EMB   300
#define KP1   320      // padded EMB (mult of 32)
#define NP1   640      // padded 2*EMB (mult of 64)
#define NP2B  384      // padded rows for w2bT (3 x 128 tiles)
#define NGRAPH 64
#define LAYERS 5
#define INV_N (1.0f / 16000.0f)

typedef unsigned short u16;
typedef unsigned int u32;
typedef __bf16 bf16_t;
typedef bf16_t bf16x8 __attribute__((ext_vector_type(8)));
typedef float f32x4 __attribute__((ext_vector_type(4)));

__device__ inline u16 f2bf(float f) {
    bf16_t b = (bf16_t)f;
    return __builtin_bit_cast(u16, b);
}
__device__ inline float bf_lo(u32 u) { return __builtin_bit_cast(float, u << 16); }
__device__ inline float bf_hi(u32 u) { return __builtin_bit_cast(float, u & 0xFFFF0000u); }
__device__ inline u32 bf_pack(float lo, float hi) {
    return ((u32)f2bf(hi) << 16) | (u32)f2bf(lo);
}

__device__ inline float softplus_f(float x) {
    return fmaxf(x, 0.f) + log1pf(expf(-fabsf(x)));
}

// async global->LDS, 16B per lane; LDS dest is wave-uniform base + lane*16
__device__ inline void gload_lds16(const u16* g, u16* l) {
    __builtin_amdgcn_global_load_lds(
        (const __attribute__((address_space(1))) void*)g,
        (__attribute__((address_space(3))) void*)l, 16, 0, 0);
}

// BN affine from raw moments: y = x*s + t
__device__ inline void bn_coef(const float* __restrict__ ssum, const float* __restrict__ ssq,
                               const float* __restrict__ g, const float* __restrict__ b,
                               int c, float& s, float& t) {
    float mean = ssum[c] * INV_N;
    float var = ssq[c] * INV_N - mean * mean;
    float rstd = rsqrtf(var + 1e-5f);
    s = rstd * g[c];
    t = b[c] - mean * s;
}

// ---------------- CSR build ----------------
__global__ void k_count(const int* __restrict__ ei, int* __restrict__ cnt) {
    int e = blockIdx.x * 256 + threadIdx.x;
    if (e >= ETOT) return;
    int dst = (e < EDGES) ? ei[EDGES + e] : (e - EDGES);
    atomicAdd(&cnt[dst], 1);
}

__global__ void k_scan(const int* cnt_in, int* row_off, int* cursor) {
    __shared__ int s[1024];
    __shared__ int carry;
    int t = threadIdx.x;
    if (t == 0) { carry = 0; row_off[0] = 0; }
    __syncthreads();
    for (int base = 0; base < NODES; base += 1024) {
        int idx = base + t;
        int v = (idx < NODES) ? cnt_in[idx] : 0;
        s[t] = v;
        __syncthreads();
        for (int off = 1; off < 1024; off <<= 1) {
            int add = (t >= off) ? s[t - off] : 0;
            __syncthreads();
            s[t] += add;
            __syncthreads();
        }
        int incl = s[t];
        int c = carry;
        if (idx < NODES) { row_off[idx + 1] = c + incl; cursor[idx] = c + incl - v; }
        __syncthreads();
        if (t == 1023) carry = c + incl;
        __syncthreads();
    }
}

__global__ void k_fill(const int* __restrict__ ei, const int* __restrict__ ea,
                       int* __restrict__ cursor, int* __restrict__ packed) {
    int e = blockIdx.x * 256 + threadIdx.x;
    if (e >= ETOT) return;
    int src, dst, c;
    if (e < EDGES) {
        src = ei[e]; dst = ei[EDGES + e];
        c = ea[e * 2] * 3 + ea[e * 2 + 1];
    } else {
        src = dst = e - EDGES; c = 15;  // self-loop attr (5,0) -> 5*3+0
    }
    int pos = atomicAdd(&cursor[dst], 1);
    packed[pos] = src | (c << 20);
}

// ---------------- setup ----------------
__global__ void k_embed(const int* __restrict__ x, const float* __restrict__ e1,
                        const float* __restrict__ e2, u16* __restrict__ h) {
    int id = blockIdx.x * 256 + threadIdx.x;
    if (id >= NODES * EMB) return;
    int i = id / EMB, f = id - i * EMB;
    h[id] = f2bf(e1[x[2 * i] * EMB + f] + e2[x[2 * i + 1] * EMB + f]);
}

__global__ void k_comb(const float* __restrict__ e1, const float* __restrict__ e2,
                       u16* __restrict__ comb) {
    int id = blockIdx.x * 256 + threadIdx.x;
    if (id >= LAYERS * 18 * EMB) return;
    int l = id / (18 * EMB);
    int r = id - l * 18 * EMB;
    int c = r / EMB, f = r - c * EMB;
    int a = c / 3, b = c - a * 3;
    comb[id] = f2bf(e1[(l * 6 + a) * EMB + f] + e2[(l * 3 + b) * EMB + f]);
}

// w1bT[l][n][k] = w1[l][k][n] as bf16, zero-padded to [640][320]
__global__ void k_convw1(const float* __restrict__ w1, u16* __restrict__ w1bT) {
    int id = blockIdx.x * 256 + threadIdx.x;
    if (id >= LAYERS * NP1 * KP1) return;
    int l = id / (NP1 * KP1);
    int r = id - l * NP1 * KP1;
    int n = r / KP1, k = r - n * KP1;
    float v = (n < 600 && k < EMB) ? w1[(l * EMB + k) * 600 + n] : 0.f;
    w1bT[id] = f2bf(v);
}

// w2bT[l][n][k] = w2[l][k][n] as bf16, zero-padded to [384][640]
__global__ void k_convw2(const float* __restrict__ w2, u16* __restrict__ w2bT) {
    int id = blockIdx.x * 256 + threadIdx.x;
    if (id >= LAYERS * NP2B * NP1) return;
    int l = id / (NP2B * NP1);
    int r = id - l * NP2B * NP1;
    int n = r / NP1, k = r - n * NP1;
    float v = (n < EMB && k < 600) ? w2[(l * 600 + k) * EMB + n] : 0.f;
    w2bT[id] = f2bf(v);
}

// ---------------- aggregation: one wave per node, bf16 h/comb, fused BN+relu ----
#define AGG_LOAD(P)                                             \
    int pk = packed[P];                                         \
    const u32* hr = hu + (size_t)(pk & 0xFFFFF) * 150;          \
    const u32* cr = cu + (pk >> 20) * 150;                      \
    u32 u0 = hr[lane], u1 = hr[64 + lane];                      \
    u32 v0 = cr[lane], v1 = cr[64 + lane];                      \
    u32 u2 = 0, v2 = 0;                                         \
    if (has2) { u2 = hr[128 + lane]; v2 = cr[128 + lane]; }

#define AGG_BN_ACC()                                            \
    a0l += fmaxf(bf_lo(u0) * s0l + t0l, 0.f) + bf_lo(v0);       \
    a0h += fmaxf(bf_hi(u0) * s0h + t0h, 0.f) + bf_hi(v0);       \
    a1l += fmaxf(bf_lo(u1) * s1l + t1l, 0.f) + bf_lo(v1);       \
    a1h += fmaxf(bf_hi(u1) * s1h + t1h, 0.f) + bf_hi(v1);       \
    a2l += fmaxf(bf_lo(u2) * s2l + t2l, 0.f) + bf_lo(v2);       \
    a2h += fmaxf(bf_hi(u2) * s2h + t2h, 0.f) + bf_hi(v2);

#define AGG_ACC()                                               \
    a0l += bf_lo(u0) + bf_lo(v0);                               \
    a0h += bf_hi(u0) + bf_hi(v0);                               \
    a1l += bf_lo(u1) + bf_lo(v1);                               \
    a1h += bf_hi(u1) + bf_hi(v1);                               \
    a2l += bf_lo(u2) + bf_lo(v2);                               \
    a2h += bf_hi(u2) + bf_hi(v2);

__global__ __launch_bounds__(256) void k_aggregate(
    const u16* __restrict__ h, const int* __restrict__ row_off,
    const int* __restrict__ packed, const u16* __restrict__ comb,
    u16* __restrict__ aggB,
    const float* __restrict__ ssum, const float* __restrict__ ssq,
    const float* __restrict__ bng, const float* __restrict__ bnb, int use_bn) {
    int node = blockIdx.x * 4 + (threadIdx.x >> 6);
    int lane = threadIdx.x & 63;
    int s = row_off[node], e = row_off[node + 1];
    bool has2 = lane < 22;  // features 256..299 = 22 uint pairs
    const u32* hu = (const u32*)h;
    const u32* cu = (const u32*)comb;
    float s0l = 1.f, t0l = 0.f, s0h = 1.f, t0h = 0.f;
    float s1l = 1.f, t1l = 0.f, s1h = 1.f, t1h = 0.f;
    float s2l = 1.f, t2l = 0.f, s2h = 1.f, t2h = 0.f;
    if (use_bn) {
        bn_coef(ssum, ssq, bng, bnb, 2 * lane,           s0l, t0l);
        bn_coef(ssum, ssq, bng, bnb, 2 * lane + 1,       s0h, t0h);
        bn_coef(ssum, ssq, bng, bnb, 128 + 2 * lane,     s1l, t1l);
        bn_coef(ssum, ssq, bng, bnb, 128 + 2 * lane + 1, s1h, t1h);
        if (has2) {
            bn_coef(ssum, ssq, bng, bnb, 256 + 2 * lane,     s2l, t2l);
            bn_coef(ssum, ssq, bng, bnb, 256 + 2 * lane + 1, s2h, t2h);
        }
    }
    float a0l = 0, a0h = 0, a1l = 0, a1h = 0, a2l = 0, a2h = 0;
    int p = s;
    if (use_bn) {
        for (; p + 1 < e; p += 2) {
            { AGG_LOAD(p); AGG_BN_ACC(); }
            { AGG_LOAD(p + 1); AGG_BN_ACC(); }
        }
        if (p < e) { AGG_LOAD(p); AGG_BN_ACC(); }
    } else {
        for (; p + 1 < e; p += 2) {
            { AGG_LOAD(p); AGG_ACC(); }
            { AGG_LOAD(p + 1); AGG_ACC(); }
        }
        if (p < e) { AGG_LOAD(p); AGG_ACC(); }
    }
    u32* o = (u32*)(aggB + (size_t)node * KP1);
    o[lane] = bf_pack(a0l, a0h);
    o[64 + lane] = bf_pack(a1l, a1h);
    if (lane < 32) o[128 + lane] = has2 ? bf_pack(a2l, a2h) : 0u;  // pads 300..319 = 0
}

// ---------------- bf16 MFMA GEMM, 128x128 tile, global_load_lds staging --------
// m97 structure: linear LDS [128][32] u16, 2 barriers/K-step, 16 MFMA/step.
// grid (N/128, M/128): N-tile on x (fastest) so consecutive blocks share A panel.
// MODE 0: +bias, relu, bf16 store (ldc stride)
// MODE 1: +bias, bf16 store (EMB stride, col<300) + fused column stats
template <int MODE>
__global__ __launch_bounds__(256) void k_gemm(
    const u16* __restrict__ A, const u16* __restrict__ Bt,
    const float* __restrict__ bias, int nbias,
    u16* __restrict__ Cv, int ldc, int K,
    float* __restrict__ ssum, float* __restrict__ ssq) {
    __shared__ __align__(16) u16 Al[128 * 32];
    __shared__ __align__(16) u16 Bl[128 * 32];
    __shared__ float rs[2][128];
    __shared__ float rq[2][128];
    int t = threadIdx.x;
    int n0 = blockIdx.x * 128, m0 = blockIdx.y * 128;
    int lane = t & 63, w = t >> 6;
    int wr = w >> 1, wc = w & 1;
    // staging: wave w owns rows [w*32, w*32+32) of A and Bt tiles, 2 chunks each.
    // lane l -> row = chunk_base + (l>>2), 16B piece (l&3); LDS linear = base + l*16B.
    int lr = lane >> 2, lc = lane & 3;
    const u16* gA0 = A + (size_t)(m0 + w * 32 + lr) * K + lc * 8;
    const u16* gA1 = gA0 + (size_t)16 * K;
    const u16* gB0 = Bt + (size_t)(n0 + w * 32 + lr) * K + lc * 8;
    const u16* gB1 = gB0 + (size_t)16 * K;
    u16* lA0 = &Al[(w * 32) * 32];
    u16* lA1 = &Al[(w * 32 + 16) * 32];
    u16* lB0 = &Bl[(w * 32) * 32];
    u16* lB1 = &Bl[(w * 32 + 16) * 32];
    f32x4 acc[4][4];
#pragma unroll
    for (int i = 0; i < 4; i++)
#pragma unroll
        for (int j = 0; j < 4; j++) acc[i][j] = (f32x4){0.f, 0.f, 0.f, 0.f};
    int fr = lane & 15;
    int k0 = (lane >> 4) * 8;
    int abase = (wr * 64 + fr) * 32 + k0;
    int bbase = (wc * 64 + fr) * 32 + k0;
    for (int kt = 0; kt < K; kt += 32) {
        if (kt) __syncthreads();  // all waves done reading LDS before overwrite
        gload_lds16(gA0 + kt, lA0);
        gload_lds16(gA1 + kt, lA1);
        gload_lds16(gB0 + kt, lB0);
        gload_lds16(gB1 + kt, lB1);
        __syncthreads();  // compiler drains vmcnt(0) before barrier -> tile visible
        bf16x8 af[4], bfv[4];
#pragma unroll
        for (int f = 0; f < 4; ++f) {
            af[f]  = *reinterpret_cast<const bf16x8*>(&Al[abase + f * 16 * 32]);
            bfv[f] = *reinterpret_cast<const bf16x8*>(&Bl[bbase + f * 16 * 32]);
        }
#pragma unroll
        for (int fm = 0; fm < 4; ++fm)
#pragma unroll
            for (int fn = 0; fn < 4; ++fn)
                acc[fm][fn] = __builtin_amdgcn_mfma_f32_16x16x32_bf16(
                    af[fm], bfv[fn], acc[fm][fn], 0, 0, 0);
    }
    int rg = lane >> 4;
    if (MODE == 0) {
#pragma unroll
        for (int fn = 0; fn < 4; ++fn) {
            int col = n0 + wc * 64 + fn * 16 + fr;
            float bv = (col < nbias) ? bias[col] : 0.f;
#pragma unroll
            for (int fm = 0; fm < 4; ++fm) {
                int rb = m0 + wr * 64 + fm * 16 + rg * 4;
#pragma unroll
                for (int j = 0; j < 4; ++j) {
                    float v = fmaxf(acc[fm][fn][j] + bv, 0.f);
                    Cv[(size_t)(rb + j) * ldc + col] = f2bf(v);
                }
            }
        }
    } else {
#pragma unroll
        for (int fn = 0; fn < 4; ++fn) {
            int col = n0 + wc * 64 + fn * 16 + fr;
            float bv = (col < nbias) ? bias[col] : 0.f;
            float cs = 0.f, cq = 0.f;
#pragma unroll
            for (int fm = 0; fm < 4; ++fm) {
                int rb = m0 + wr * 64 + fm * 16 + rg * 4;
#pragma unroll
                for (int j = 0; j < 4; ++j) {
                    float v = acc[fm][fn][j] + bv;
                    if (col < EMB) Cv[(size_t)(rb + j) * EMB + col] = f2bf(v);
                    cs += v;
                    cq += v * v;
                }
            }
            cs += __shfl_xor(cs, 16); cs += __shfl_xor(cs, 32);
            cq += __shfl_xor(cq, 16); cq += __shfl_xor(cq, 32);
            if (rg == 0) {
                rs[wr][wc * 64 + fn * 16 + fr] = cs;
                rq[wr][wc * 64 + fn * 16 + fr] = cq;
            }
        }
        __syncthreads();
        if (t < 128) {
            int col = n0 + t;
            if (col < EMB) {
                atomicAdd(&ssum[col], rs[0][t] + rs[1][t]);
                atomicAdd(&ssq[col], rq[0][t] + rq[1][t]);
            }
        }
    }
}

// ---------------- tail: graph offsets, pool (fused final BN), head GEMMs -------
__global__ void k_goff(const int* __restrict__ batch, int* __restrict__ goff) {
    int t = threadIdx.x;
    if (t > NGRAPH) return;
    int lo = 0, hi = NODES;
    while (lo < hi) { int mid = (lo + hi) >> 1; if (batch[mid] < t) lo = mid + 1; else hi = mid; }
    goff[t] = lo;
}

// grid (NGRAPH, 5); h holds PRE-BN bf16 layer-4 output; affine applied post-mean.
__global__ __launch_bounds__(256) void k_pool(const u16* __restrict__ h,
                                              const int* __restrict__ goff,
                                              const float* __restrict__ ssum,
                                              const float* __restrict__ ssq,
                                              const float* __restrict__ bng,
                                              const float* __restrict__ bnb,
                                              float* __restrict__ hg) {
    __shared__ float red[4][64];
    int g = blockIdx.x;
    int col = blockIdx.y * 64 + (threadIdx.x & 63);
    int w = threadIdx.x >> 6;
    int s = goff[g], e = goff[g + 1];
    float a = 0.f;
    bool ok = col < EMB;
    if (ok) {
        for (int r = s + w; r < e; r += 4)
            a += __builtin_bit_cast(float, (u32)h[(size_t)r * EMB + col] << 16);
    }
    red[w][threadIdx.x & 63] = a;
    __syncthreads();
    if (w == 0 && ok) {
        float sc, tc;
        bn_coef(ssum, ssq, bng, bnb, col, sc, tc);
        float v = red[0][threadIdx.x] + red[1][threadIdx.x] +
                  red[2][threadIdx.x] + red[3][threadIdx.x];
        float inv = (e > s) ? 1.0f / (float)(e - s) : 0.f;
        hg[(size_t)g * EMB + col] = (v * inv) * sc + tc;
    }
}

// C[row, col] = act(A[row,:K] @ W[:K, col] + b[col]); grid (M, N/64), block 256.
template <int ACT>  // 0: none, 1: softplus
__global__ __launch_bounds__(256) void k_small_mm(
    const float* __restrict__ A, const float* __restrict__ W,
    const float* __restrict__ bias, float* __restrict__ C, int N, int K) {
    __shared__ float red[4][64];
    int row = blockIdx.x;
    int lane = threadIdx.x & 63;
    int col = blockIdx.y * 64 + lane;
    int w = threadIdx.x >> 6;
    const float* a = A + (size_t)row * K;
    float acc = 0.f;
#pragma unroll 4
    for (int k = w; k < K; k += 4) acc += a[k] * W[(size_t)k * N + col];
    red[w][lane] = acc;
    __syncthreads();
    if (w == 0) {
        float v = red[0][lane] + red[1][lane] + red[2][lane] + red[3][lane] + bias[col];
        if (ACT) v = softplus_f(v);
        C[(size_t)row * N + col] = v;
    }
}

// pred[g, 0:2] = P[g,:256] @ hw3 + hb3 ; one block per graph
__global__ __launch_bounds__(256) void k_pred(const float* __restrict__ P,
                                              const float* __restrict__ hw3,
                                              const float* __restrict__ hb3,
                                              float* __restrict__ out) {
    __shared__ float red[2][4];
    int g = blockIdx.x;
    int t = threadIdx.x;
    float q = P[(size_t)g * 256 + t];
    float r0 = q * hw3[t * 2 + 0];
    float r1 = q * hw3[t * 2 + 1];
#pragma unroll
    for (int off = 32; off > 0; off >>= 1) {
        r0 += __shfl_down(r0, off);
        r1 += __shfl_down(r1, off);
    }
    if ((t & 63) == 0) { red[0][t >> 6] = r0; red[1][t >> 6] = r1; }
    __syncthreads();
    if (t == 0) {
        out[(size_t)NGRAPH * 512 + g * 2 + 0] = red[0][0] + red[0][1] + red[0][2] + red[0][3] + hb3[0];
        out[(size_t)NGRAPH * 512 + g * 2 + 1] = red[1][0] + red[1][1] + red[1][2] + red[1][3] + hb3[1];
    }
}

// ---------------- launch ----------------
extern "C" void kernel_launch(void* const* d_in, const int* in_sizes, int n_in,
                              void* d_out, int out_size, void* d_ws, size_t ws_size,
                              hipStream_t stream) {
    const int* x      = (const int*)d_in[0];
    const int* ei     = (const int*)d_in[1];
    const int* ea     = (const int*)d_in[2];
    const int* batch  = (const int*)d_in[3];
    const float* x_emb1 = (const float*)d_in[4];
    const float* x_emb2 = (const float*)d_in[5];
    const float* e1_emb = (const float*)d_in[6];
    const float* e2_emb = (const float*)d_in[7];
    const float* w1   = (const float*)d_in[8];
    const float* b1   = (const float*)d_in[9];
    const float* w2   = (const float*)d_in[10];
    const float* b2   = (const float*)d_in[11];
    const float* bn_g = (const float*)d_in[12];
    const float* bn_b = (const float*)d_in[13];
    const float* feat_w = (const float*)d_in[14];
    const float* feat_b = (const float*)d_in[15];
    const float* hw1  = (const float*)d_in[16];
    const float* hb1  = (const float*)d_in[17];
    const float* hw2  = (const float*)d_in[18];
    const float* hb2  = (const float*)d_in[19];
    const float* hw3  = (const float*)d_in[20];
    const float* hb3  = (const float*)d_in[21];
    float* out = (float*)d_out;

    char* p = (char*)d_ws;
    auto alloc = [&](size_t bytes) -> char* {
        char* r = p;
        p += ((bytes + 255) / 256) * 256;
        return r;
    };
    u16* h_a     = (u16*)alloc((size_t)NODES * EMB * 2);
    u16* h_b     = (u16*)alloc((size_t)NODES * EMB * 2);
    u16* aggB    = (u16*)alloc((size_t)NODES * KP1 * 2);
    u16* T       = (u16*)alloc((size_t)NODES * NP1 * 2);
    u16* w1bT    = (u16*)alloc((size_t)LAYERS * NP1 * KP1 * 2);
    u16* w2bT    = (u16*)alloc((size_t)LAYERS * NP2B * NP1 * 2);
    u16* comb    = (u16*)alloc((size_t)LAYERS * 18 * EMB * 2);
    int* row_off = (int*)alloc((NODES + 1) * 4);
    int* cursor  = (int*)alloc(NODES * 4);
    int* packed  = (int*)alloc((size_t)ETOT * 4);
    float* stats = (float*)alloc(2 * 304 * 4);
    int* goff    = (int*)alloc((NGRAPH + 1) * 4);
    float* hg    = (float*)alloc((size_t)NGRAPH * EMB * 4);
    float* pb1   = (float*)alloc((size_t)NGRAPH * 256 * 4);
    float* pb2   = (float*)alloc((size_t)NGRAPH * 256 * 4);
    if ((size_t)(p - (char*)d_ws) > ws_size) return;  // workspace too small

    float* ssum = stats;
    float* ssq  = stats + 304;

    // CSR build (once; shared across layers)
    hipMemsetAsync(cursor, 0, NODES * 4, stream);
    k_count<<<(ETOT + 255) / 256, 256, 0, stream>>>(ei, cursor);
    k_scan<<<1, 1024, 0, stream>>>(cursor, row_off, cursor);
    k_fill<<<(ETOT + 255) / 256, 256, 0, stream>>>(ei, ea, cursor, packed);

    k_embed<<<(NODES * EMB + 255) / 256, 256, 0, stream>>>(x, x_emb1, x_emb2, h_a);
    k_comb<<<(LAYERS * 18 * EMB + 255) / 256, 256, 0, stream>>>(e1_emb, e2_emb, comb);
    k_convw1<<<(LAYERS * NP1 * KP1 + 255) / 256, 256, 0, stream>>>(w1, w1bT);
    k_convw2<<<(LAYERS * NP2B * NP1 + 255) / 256, 256, 0, stream>>>(w2, w2bT);
    k_goff<<<1, 128, 0, stream>>>(batch, goff);

    for (int l = 0; l < LAYERS; ++l) {
        const u16* h_in = (l & 1) ? h_b : h_a;
        u16* h_out      = (l & 1) ? h_a : h_b;
        // aggregate consumes h_in with the PREVIOUS layer's BN(+relu) fused (l>0)
        k_aggregate<<<NODES / 4, 256, 0, stream>>>(
            h_in, row_off, packed, comb + (size_t)l * 18 * EMB, aggB,
            ssum, ssq, bn_g + (l > 0 ? (l - 1) * EMB : 0), bn_b + (l > 0 ? (l - 1) * EMB : 0),
            l > 0 ? 1 : 0);
        k_gemm<0><<<dim3(NP1 / 128, NODES / 128), 256, 0, stream>>>(
            aggB, w1bT + (size_t)l * NP1 * KP1, b1 + l * 600, 600, T, NP1, KP1,
            nullptr, nullptr);
        hipMemsetAsync(stats, 0, 2 * 304 * 4, stream);
        k_gemm<1><<<dim3(NP2B / 128, NODES / 128), 256, 0, stream>>>(
            T, w2bT + (size_t)l * NP2B * NP1, b2 + l * EMB, EMB, h_out, 0, NP1,
            ssum, ssq);
    }

    const u16* h_fin = h_b;  // layer 4 wrote h_b (pre-BN); pool applies BN affine
    k_pool<<<dim3(NGRAPH, 5), 256, 0, stream>>>(h_fin, goff, ssum, ssq,
                                                bn_g + 4 * EMB, bn_b + 4 * EMB, hg);
    k_small_mm<0><<<dim3(NGRAPH, 8), 256, 0, stream>>>(hg, feat_w, feat_b, out, 512, EMB);
    k_small_mm<1><<<dim3(NGRAPH, 4), 256, 0, stream>>>(out, hw1, hb1, pb1, 256, 512);
    k_small_mm<1><<<dim3(NGRAPH, 4), 256, 0, stream>>>(pb1, hw2, hb2, pb2, 256, 256);
    k_pred<<<NGRAPH, 256, 0, stream>>>(pb2, hw3, hb3, out);
}

// Round 7
// 495.466 us; speedup vs baseline: 2.8443x; 1.0729x over previous
//
#include <hip/hip_runtime.h>

#define NODES 16000
#define EDGES 256000
#define ETOT  272000   // EDGES + NODES self-loops
#define EMB   300
#define KP1   320      // padded EMB (mult of 32)
#define NP1   640      // padded 2*EMB (mult of 64)
#define NP2B  384      // padded rows for w2bT (3 x 128 tiles)
#define NGRAPH 64
#define LAYERS 5
#define INV_N (1.0f / 16000.0f)

typedef unsigned short u16;
typedef unsigned int u32;
typedef __bf16 bf16_t;
typedef bf16_t bf16x8 __attribute__((ext_vector_type(8)));
typedef float f32x4 __attribute__((ext_vector_type(4)));

__device__ inline u16 f2bf(float f) {
    bf16_t b = (bf16_t)f;
    return __builtin_bit_cast(u16, b);
}
__device__ inline float bf_lo(u32 u) { return __builtin_bit_cast(float, u << 16); }
__device__ inline float bf_hi(u32 u) { return __builtin_bit_cast(float, u & 0xFFFF0000u); }
__device__ inline u32 bf_pack(float lo, float hi) {
    return ((u32)f2bf(hi) << 16) | (u32)f2bf(lo);
}

__device__ inline float softplus_f(float x) {
    return fmaxf(x, 0.f) + log1pf(expf(-fabsf(x)));
}

// async global->LDS, 16B per lane; LDS dest is wave-uniform base + lane*16
__device__ inline void gload_lds16(const u16* g, u16* l) {
    __builtin_amdgcn_global_load_lds(
        (const __attribute__((address_space(1))) void*)g,
        (__attribute__((address_space(3))) void*)l, 16, 0, 0);
}

// BN affine from raw moments: y = x*s + t
__device__ inline void bn_coef_v(float ss, float qq, float gg, float bb,
                                 float& s, float& t) {
    float mean = ss * INV_N;
    float var = qq * INV_N - mean * mean;
    float rstd = rsqrtf(var + 1e-5f);
    s = rstd * gg;
    t = bb - mean * s;
}

// ---------------- CSR build ----------------
__global__ void k_count(const int* __restrict__ ei, int* __restrict__ cnt) {
    int e = blockIdx.x * 256 + threadIdx.x;
    if (e >= ETOT) return;
    int dst = (e < EDGES) ? ei[EDGES + e] : (e - EDGES);
    atomicAdd(&cnt[dst], 1);
}

// 1024 threads, 16 nodes/thread; wave shuffle-scan + LDS wave-prefix, 1 barrier.
__global__ __launch_bounds__(1024) void k_scan(const int* __restrict__ cnt,
                                               int* __restrict__ row_off,
                                               int* __restrict__ cursor) {
    __shared__ int wsum[16];
    int t = threadIdx.x;
    int lane = t & 63, w = t >> 6;
    int base = t * 16;
    int pre[16];
    int run = 0;
#pragma unroll
    for (int i = 0; i < 16; ++i) {
        int idx = base + i;
        int v = (idx < NODES) ? cnt[idx] : 0;
        pre[i] = run;
        run += v;
    }
    int inc = run;
#pragma unroll
    for (int off = 1; off < 64; off <<= 1) {
        int n = __shfl_up(inc, off);
        if (lane >= off) inc += n;
    }
    if (lane == 63) wsum[w] = inc;
    __syncthreads();
    int wpre = 0;
    for (int i = 0; i < w; ++i) wpre += wsum[i];
    int excl = wpre + inc - run;
#pragma unroll
    for (int i = 0; i < 16; ++i) {
        int idx = base + i;
        if (idx < NODES) {
            int st = excl + pre[i];
            row_off[idx] = st;
            cursor[idx] = st;
        }
    }
    if (t == 1023) row_off[NODES] = wpre + inc;
}

__global__ void k_fill(const int* __restrict__ ei, const int* __restrict__ ea,
                       int* __restrict__ cursor, int* __restrict__ packed) {
    int e = blockIdx.x * 256 + threadIdx.x;
    if (e >= ETOT) return;
    int src, dst, c;
    if (e < EDGES) {
        src = ei[e]; dst = ei[EDGES + e];
        c = ea[e * 2] * 3 + ea[e * 2 + 1];
    } else {
        src = dst = e - EDGES; c = 15;  // self-loop attr (5,0) -> 5*3+0
    }
    int pos = atomicAdd(&cursor[dst], 1);
    packed[pos] = src | (c << 20);
}

// ---------------- fused setup: embed | comb | convw1 | convw2 | goff ----------
#define SEG0 1200000   // embed: NODES*EMB/4
#define SEG1 6750      // comb: 5*18*75
#define SEG2 256000    // convw1: 5*640*80
#define SEG3 307200    // convw2: 5*384*160
#define SETUP_TOT (SEG0 + SEG1 + SEG2 + SEG3 + NGRAPH + 1)

__global__ __launch_bounds__(256) void k_setup(
    const int* __restrict__ x, const float* __restrict__ e1x,
    const float* __restrict__ e2x, const float* __restrict__ ce1,
    const float* __restrict__ ce2, const float* __restrict__ w1,
    const float* __restrict__ w2, const int* __restrict__ batch,
    u16* __restrict__ h, u16* __restrict__ comb,
    u16* __restrict__ w1bT, u16* __restrict__ w2bT, int* __restrict__ goff) {
    int id = blockIdx.x * 256 + threadIdx.x;
    if (id < SEG0) {
        int base = id * 4;
        int row = base / EMB;
        int f = base - row * EMB;
        int x1 = x[2 * row], x2 = x[2 * row + 1];
        float4 a = *(const float4*)(e1x + x1 * EMB + f);
        float4 b = *(const float4*)(e2x + x2 * EMB + f);
        u32* o = (u32*)h + id * 2;
        o[0] = bf_pack(a.x + b.x, a.y + b.y);
        o[1] = bf_pack(a.z + b.z, a.w + b.w);
        return;
    }
    id -= SEG0;
    if (id < SEG1) {
        int l = id / 1350, r = id - l * 1350;
        int c = r / 75, f = (r - c * 75) * 4;
        int a = c / 3, bb = c - a * 3;
        float4 va = *(const float4*)(ce1 + (l * 6 + a) * EMB + f);
        float4 vb = *(const float4*)(ce2 + (l * 3 + bb) * EMB + f);
        u32* o = (u32*)comb + ((l * 18 + c) * EMB + f) / 2;
        o[0] = bf_pack(va.x + vb.x, va.y + vb.y);
        o[1] = bf_pack(va.z + vb.z, va.w + vb.w);
        return;
    }
    id -= SEG1;
    if (id < SEG2) {  // w1bT[l][n][k] = w1[l][k][n], pad to [640][320]
        int l = id / (NP1 * 80), r = id - l * (NP1 * 80);
        int n = r / 80, k4 = (r - n * 80) * 4;
        float v[4];
#pragma unroll
        for (int j = 0; j < 4; ++j) {
            int k = k4 + j;
            v[j] = (n < 600 && k < EMB) ? w1[(l * EMB + k) * 600 + n] : 0.f;
        }
        u32* o = (u32*)w1bT + ((size_t)(l * NP1 + n) * KP1 + k4) / 2;
        o[0] = bf_pack(v[0], v[1]);
        o[1] = bf_pack(v[2], v[3]);
        return;
    }
    id -= SEG2;
    if (id < SEG3) {  // w2bT[l][n][k] = w2[l][k][n], pad to [384][640]
        int l = id / (NP2B * 160), r = id - l * (NP2B * 160);
        int n = r / 160, k4 = (r - n * 160) * 4;
        float v[4];
#pragma unroll
        for (int j = 0; j < 4; ++j) {
            int k = k4 + j;
            v[j] = (n < EMB && k < 600) ? w2[(l * 600 + k) * EMB + n] : 0.f;
        }
        u32* o = (u32*)w2bT + ((size_t)(l * NP2B + n) * NP1 + k4) / 2;
        o[0] = bf_pack(v[0], v[1]);
        o[1] = bf_pack(v[2], v[3]);
        return;
    }
    id -= SEG3;
    if (id <= NGRAPH) {
        int lo = 0, hi = NODES;
        while (lo < hi) { int mid = (lo + hi) >> 1; if (batch[mid] < id) lo = mid + 1; else hi = mid; }
        goff[id] = lo;
    }
}

// ---------------- BN+relu hoisted: h' = relu(h*s + t), bf16->bf16, 4 elems/thr -
__global__ __launch_bounds__(256) void k_bnrelu(
    const u16* __restrict__ hin, u16* __restrict__ hout,
    const float* __restrict__ ssum, const float* __restrict__ ssq,
    const float* __restrict__ g, const float* __restrict__ b) {
    int id = blockIdx.x * 256 + threadIdx.x;
    if (id >= NODES * EMB / 4) return;
    int base = id * 4;
    int row = base / EMB;
    int f = base - row * EMB;  // f % 4 == 0 since 4 | 300
    float4 S = *(const float4*)(ssum + f);
    float4 Q = *(const float4*)(ssq + f);
    float4 G = *(const float4*)(g + f);
    float4 B = *(const float4*)(b + f);
    const u32* in = (const u32*)hin + id * 2;
    u32 x0 = in[0], x1 = in[1];
    float sc0, tc0, sc1, tc1, sc2, tc2, sc3, tc3;
    bn_coef_v(S.x, Q.x, G.x, B.x, sc0, tc0);
    bn_coef_v(S.y, Q.y, G.y, B.y, sc1, tc1);
    bn_coef_v(S.z, Q.z, G.z, B.z, sc2, tc2);
    bn_coef_v(S.w, Q.w, G.w, B.w, sc3, tc3);
    float v0 = fmaxf(bf_lo(x0) * sc0 + tc0, 0.f);
    float v1 = fmaxf(bf_hi(x0) * sc1 + tc1, 0.f);
    float v2 = fmaxf(bf_lo(x1) * sc2 + tc2, 0.f);
    float v3 = fmaxf(bf_hi(x1) * sc3 + tc3, 0.f);
    u32* o = (u32*)hout + id * 2;
    o[0] = bf_pack(v0, v1);
    o[1] = bf_pack(v2, v3);
}

// ---------------- aggregation: one wave per node, bf16, no BN (hoisted) --------
#define AGG_LOAD(P)                                             \
    int pk = packed[P];                                         \
    const u32* hr = hu + (size_t)(pk & 0xFFFFF) * 150;          \
    const u32* cr = cu + (pk >> 20) * 150;                      \
    u32 u0 = hr[lane], u1 = hr[64 + lane];                      \
    u32 v0 = cr[lane], v1 = cr[64 + lane];                      \
    u32 u2 = 0, v2 = 0;                                         \
    if (has2) { u2 = hr[128 + lane]; v2 = cr[128 + lane]; }

#define AGG_ACC()                                               \
    a0l += bf_lo(u0) + bf_lo(v0);                               \
    a0h += bf_hi(u0) + bf_hi(v0);                               \
    a1l += bf_lo(u1) + bf_lo(v1);                               \
    a1h += bf_hi(u1) + bf_hi(v1);                               \
    a2l += bf_lo(u2) + bf_lo(v2);                               \
    a2h += bf_hi(u2) + bf_hi(v2);

__global__ __launch_bounds__(256) void k_aggregate(
    const u16* __restrict__ h, const int* __restrict__ row_off,
    const int* __restrict__ packed, const u16* __restrict__ comb,
    u16* __restrict__ aggB) {
    int node = blockIdx.x * 4 + (threadIdx.x >> 6);
    int lane = threadIdx.x & 63;
    int s = row_off[node], e = row_off[node + 1];
    bool has2 = lane < 22;  // features 256..299 = 22 uint pairs
    const u32* hu = (const u32*)h;
    const u32* cu = (const u32*)comb;
    float a0l = 0, a0h = 0, a1l = 0, a1h = 0, a2l = 0, a2h = 0;
    int p = s;
    for (; p + 3 < e; p += 4) {
        { AGG_LOAD(p);     AGG_ACC(); }
        { AGG_LOAD(p + 1); AGG_ACC(); }
        { AGG_LOAD(p + 2); AGG_ACC(); }
        { AGG_LOAD(p + 3); AGG_ACC(); }
    }
    for (; p < e; ++p) { AGG_LOAD(p); AGG_ACC(); }
    u32* o = (u32*)(aggB + (size_t)node * KP1);
    o[lane] = bf_pack(a0l, a0h);
    o[64 + lane] = bf_pack(a1l, a1h);
    if (lane < 32) o[128 + lane] = has2 ? bf_pack(a2l, a2h) : 0u;  // pads 300..319
}

// ---------------- bf16 MFMA GEMM, 128x128 tile, global_load_lds staging --------
// m97 structure: linear LDS [128][32] u16, 2 barriers/K-step, 16 MFMA/step.
// grid (N/128, M/128): N-tile on x (fastest) so consecutive blocks share A panel.
// MODE 0: +bias, relu, bf16 store (ldc stride)
// MODE 1: +bias, bf16 store (EMB stride, col<300) + fused column stats
template <int MODE>
__global__ __launch_bounds__(256) void k_gemm(
    const u16* __restrict__ A, const u16* __restrict__ Bt,
    const float* __restrict__ bias, int nbias,
    u16* __restrict__ Cv, int ldc, int K,
    float* __restrict__ ssum, float* __restrict__ ssq) {
    __shared__ __align__(16) u16 Al[128 * 32];
    __shared__ __align__(16) u16 Bl[128 * 32];
    __shared__ float rs[2][128];
    __shared__ float rq[2][128];
    int t = threadIdx.x;
    int n0 = blockIdx.x * 128, m0 = blockIdx.y * 128;
    int lane = t & 63, w = t >> 6;
    int wr = w >> 1, wc = w & 1;
    int lr = lane >> 2, lc = lane & 3;
    const u16* gA0 = A + (size_t)(m0 + w * 32 + lr) * K + lc * 8;
    const u16* gA1 = gA0 + (size_t)16 * K;
    const u16* gB0 = Bt + (size_t)(n0 + w * 32 + lr) * K + lc * 8;
    const u16* gB1 = gB0 + (size_t)16 * K;
    u16* lA0 = &Al[(w * 32) * 32];
    u16* lA1 = &Al[(w * 32 + 16) * 32];
    u16* lB0 = &Bl[(w * 32) * 32];
    u16* lB1 = &Bl[(w * 32 + 16) * 32];
    f32x4 acc[4][4];
#pragma unroll
    for (int i = 0; i < 4; i++)
#pragma unroll
        for (int j = 0; j < 4; j++) acc[i][j] = (f32x4){0.f, 0.f, 0.f, 0.f};
    int fr = lane & 15;
    int k0 = (lane >> 4) * 8;
    int abase = (wr * 64 + fr) * 32 + k0;
    int bbase = (wc * 64 + fr) * 32 + k0;
    for (int kt = 0; kt < K; kt += 32) {
        if (kt) __syncthreads();
        gload_lds16(gA0 + kt, lA0);
        gload_lds16(gA1 + kt, lA1);
        gload_lds16(gB0 + kt, lB0);
        gload_lds16(gB1 + kt, lB1);
        __syncthreads();
        bf16x8 af[4], bfv[4];
#pragma unroll
        for (int f = 0; f < 4; ++f) {
            af[f]  = *reinterpret_cast<const bf16x8*>(&Al[abase + f * 16 * 32]);
            bfv[f] = *reinterpret_cast<const bf16x8*>(&Bl[bbase + f * 16 * 32]);
        }
#pragma unroll
        for (int fm = 0; fm < 4; ++fm)
#pragma unroll
            for (int fn = 0; fn < 4; ++fn)
                acc[fm][fn] = __builtin_amdgcn_mfma_f32_16x16x32_bf16(
                    af[fm], bfv[fn], acc[fm][fn], 0, 0, 0);
    }
    int rg = lane >> 4;
    if (MODE == 0) {
#pragma unroll
        for (int fn = 0; fn < 4; ++fn) {
            int col = n0 + wc * 64 + fn * 16 + fr;
            float bv = (col < nbias) ? bias[col] : 0.f;
#pragma unroll
            for (int fm = 0; fm < 4; ++fm) {
                int rb = m0 + wr * 64 + fm * 16 + rg * 4;
#pragma unroll
                for (int j = 0; j < 4; ++j) {
                    float v = fmaxf(acc[fm][fn][j] + bv, 0.f);
                    Cv[(size_t)(rb + j) * ldc + col] = f2bf(v);
                }
            }
        }
    } else {
#pragma unroll
        for (int fn = 0; fn < 4; ++fn) {
            int col = n0 + wc * 64 + fn * 16 + fr;
            float bv = (col < nbias) ? bias[col] : 0.f;
            float cs = 0.f, cq = 0.f;
#pragma unroll
            for (int fm = 0; fm < 4; ++fm) {
                int rb = m0 + wr * 64 + fm * 16 + rg * 4;
#pragma unroll
                for (int j = 0; j < 4; ++j) {
                    float v = acc[fm][fn][j] + bv;
                    if (col < EMB) Cv[(size_t)(rb + j) * EMB + col] = f2bf(v);
                    cs += v;
                    cq += v * v;
                }
            }
            cs += __shfl_xor(cs, 16); cs += __shfl_xor(cs, 32);
            cq += __shfl_xor(cq, 16); cq += __shfl_xor(cq, 32);
            if (rg == 0) {
                rs[wr][wc * 64 + fn * 16 + fr] = cs;
                rq[wr][wc * 64 + fn * 16 + fr] = cq;
            }
        }
        __syncthreads();
        if (t < 128) {
            int col = n0 + t;
            if (col < EMB) {
                atomicAdd(&ssum[col], rs[0][t] + rs[1][t]);
                atomicAdd(&ssq[col], rq[0][t] + rq[1][t]);
            }
        }
    }
}

// ---------------- tail: pool (fused final BN), head GEMMs ----------------------
__global__ __launch_bounds__(256) void k_pool(const u16* __restrict__ h,
                                              const int* __restrict__ goff,
                                              const float* __restrict__ ssum,
                                              const float* __restrict__ ssq,
                                              const float* __restrict__ bng,
                                              const float* __restrict__ bnb,
                                              float* __restrict__ hg) {
    __shared__ float red[4][64];
    int g = blockIdx.x;
    int col = blockIdx.y * 64 + (threadIdx.x & 63);
    int w = threadIdx.x >> 6;
    int s = goff[g], e = goff[g + 1];
    float a = 0.f;
    bool ok = col < EMB;
    if (ok) {
        for (int r = s + w; r < e; r += 4)
            a += __builtin_bit_cast(float, (u32)h[(size_t)r * EMB + col] << 16);
    }
    red[w][threadIdx.x & 63] = a;
    __syncthreads();
    if (w == 0 && ok) {
        float sc, tc;
        bn_coef_v(ssum[col], ssq[col], bng[col], bnb[col], sc, tc);
        float v = red[0][threadIdx.x] + red[1][threadIdx.x] +
                  red[2][threadIdx.x] + red[3][threadIdx.x];
        float inv = (e > s) ? 1.0f / (float)(e - s) : 0.f;
        hg[(size_t)g * EMB + col] = (v * inv) * sc + tc;
    }
}

template <int ACT>  // 0: none, 1: softplus
__global__ __launch_bounds__(256) void k_small_mm(
    const float* __restrict__ A, const float* __restrict__ W,
    const float* __restrict__ bias, float* __restrict__ C, int N, int K) {
    __shared__ float red[4][64];
    int row = blockIdx.x;
    int lane = threadIdx.x & 63;
    int col = blockIdx.y * 64 + lane;
    int w = threadIdx.x >> 6;
    const float* a = A + (size_t)row * K;
    float acc = 0.f;
#pragma unroll 4
    for (int k = w; k < K; k += 4) acc += a[k] * W[(size_t)k * N + col];
    red[w][lane] = acc;
    __syncthreads();
    if (w == 0) {
        float v = red[0][lane] + red[1][lane] + red[2][lane] + red[3][lane] + bias[col];
        if (ACT) v = softplus_f(v);
        C[(size_t)row * N + col] = v;
    }
}

__global__ __launch_bounds__(256) void k_pred(const float* __restrict__ P,
                                              const float* __restrict__ hw3,
                                              const float* __restrict__ hb3,
                                              float* __restrict__ out) {
    __shared__ float red[2][4];
    int g = blockIdx.x;
    int t = threadIdx.x;
    float q = P[(size_t)g * 256 + t];
    float r0 = q * hw3[t * 2 + 0];
    float r1 = q * hw3[t * 2 + 1];
#pragma unroll
    for (int off = 32; off > 0; off >>= 1) {
        r0 += __shfl_down(r0, off);
        r1 += __shfl_down(r1, off);
    }
    if ((t & 63) == 0) { red[0][t >> 6] = r0; red[1][t >> 6] = r1; }
    __syncthreads();
    if (t == 0) {
        out[(size_t)NGRAPH * 512 + g * 2 + 0] = red[0][0] + red[0][1] + red[0][2] + red[0][3] + hb3[0];
        out[(size_t)NGRAPH * 512 + g * 2 + 1] = red[1][0] + red[1][1] + red[1][2] + red[1][3] + hb3[1];
    }
}

// ---------------- launch ----------------
extern "C" void kernel_launch(void* const* d_in, const int* in_sizes, int n_in,
                              void* d_out, int out_size, void* d_ws, size_t ws_size,
                              hipStream_t stream) {
    const int* x      = (const int*)d_in[0];
    const int* ei     = (const int*)d_in[1];
    const int* ea     = (const int*)d_in[2];
    const int* batch  = (const int*)d_in[3];
    const float* x_emb1 = (const float*)d_in[4];
    const float* x_emb2 = (const float*)d_in[5];
    const float* e1_emb = (const float*)d_in[6];
    const float* e2_emb = (const float*)d_in[7];
    const float* w1   = (const float*)d_in[8];
    const float* b1   = (const float*)d_in[9];
    const float* w2   = (const float*)d_in[10];
    const float* b2   = (const float*)d_in[11];
    const float* bn_g = (const float*)d_in[12];
    const float* bn_b = (const float*)d_in[13];
    const float* feat_w = (const float*)d_in[14];
    const float* feat_b = (const float*)d_in[15];
    const float* hw1  = (const float*)d_in[16];
    const float* hb1  = (const float*)d_in[17];
    const float* hw2  = (const float*)d_in[18];
    const float* hb2  = (const float*)d_in[19];
    const float* hw3  = (const float*)d_in[20];
    const float* hb3  = (const float*)d_in[21];
    float* out = (float*)d_out;

    char* p = (char*)d_ws;
    auto alloc = [&](size_t bytes) -> char* {
        char* r = p;
        p += ((bytes + 255) / 256) * 256;
        return r;
    };
    u16* h_a     = (u16*)alloc((size_t)NODES * EMB * 2);   // current h (pre-BN)
    u16* h_b     = (u16*)alloc((size_t)NODES * EMB * 2);   // post-BN h'
    u16* aggB    = (u16*)alloc((size_t)NODES * KP1 * 2);
    u16* T       = (u16*)alloc((size_t)NODES * NP1 * 2);
    u16* w1bT    = (u16*)alloc((size_t)LAYERS * NP1 * KP1 * 2);
    u16* w2bT    = (u16*)alloc((size_t)LAYERS * NP2B * NP1 * 2);
    u16* comb    = (u16*)alloc((size_t)LAYERS * 18 * EMB * 2);
    int* row_off = (int*)alloc((NODES + 1) * 4);
    int* packed  = (int*)alloc((size_t)ETOT * 4);
    int* goff    = (int*)alloc((NGRAPH + 1) * 4);
    float* hg    = (float*)alloc((size_t)NGRAPH * EMB * 4);
    float* pb1   = (float*)alloc((size_t)NGRAPH * 256 * 4);
    float* pb2   = (float*)alloc((size_t)NGRAPH * 256 * 4);
    // cursor + per-layer stats contiguous -> single memset
    int* cursor  = (int*)alloc(NODES * 4);                 // 64000 B (256-mult)
    float* stats5 = (float*)alloc((size_t)LAYERS * 640 * 4);  // [l][ssum320|ssq320]
    if ((size_t)(p - (char*)d_ws) > ws_size) return;  // workspace too small

    hipMemsetAsync(cursor, 0, NODES * 4 + LAYERS * 640 * 4, stream);

    // CSR build (once; shared across layers)
    k_count<<<(ETOT + 255) / 256, 256, 0, stream>>>(ei, cursor);
    k_scan<<<1, 1024, 0, stream>>>(cursor, row_off, cursor);
    k_fill<<<(ETOT + 255) / 256, 256, 0, stream>>>(ei, ea, cursor, packed);

    // fused setup: embed -> h_a, comb, w1bT, w2bT, goff
    k_setup<<<(SETUP_TOT + 255) / 256, 256, 0, stream>>>(
        x, x_emb1, x_emb2, e1_emb, e2_emb, w1, w2, batch,
        h_a, comb, w1bT, w2bT, goff);

    for (int l = 0; l < LAYERS; ++l) {
        const u16* h_src;
        if (l == 0) {
            h_src = h_a;
        } else {
            float* st = stats5 + (size_t)(l - 1) * 640;
            k_bnrelu<<<(NODES * EMB / 4 + 255) / 256, 256, 0, stream>>>(
                h_a, h_b, st, st + 320, bn_g + (l - 1) * EMB, bn_b + (l - 1) * EMB);
            h_src = h_b;
        }
        k_aggregate<<<NODES / 4, 256, 0, stream>>>(
            h_src, row_off, packed, comb + (size_t)l * 18 * EMB, aggB);
        k_gemm<0><<<dim3(NP1 / 128, NODES / 128), 256, 0, stream>>>(
            aggB, w1bT + (size_t)l * NP1 * KP1, b1 + l * 600, 600, T, NP1, KP1,
            nullptr, nullptr);
        float* st = stats5 + (size_t)l * 640;
        k_gemm<1><<<dim3(NP2B / 128, NODES / 128), 256, 0, stream>>>(
            T, w2bT + (size_t)l * NP2B * NP1, b2 + l * EMB, EMB, h_a, 0, NP1,
            st, st + 320);
    }

    // h_a holds layer-4 pre-BN output; pool applies BN affine post-mean
    float* st4 = stats5 + (size_t)4 * 640;
    k_pool<<<dim3(NGRAPH, 5), 256, 0, stream>>>(h_a, goff, st4, st4 + 320,
                                                bn_g + 4 * EMB, bn_b + 4 * EMB, hg);
    k_small_mm<0><<<dim3(NGRAPH, 8), 256, 0, stream>>>(hg, feat_w, feat_b, out, 512, EMB);
    k_small_mm<1><<<dim3(NGRAPH, 4), 256, 0, stream>>>(out, hw1, hb1, pb1, 256, 512);
    k_small_mm<1><<<dim3(NGRAPH, 4), 256, 0, stream>>>(pb1, hw2, hb2, pb2, 256, 256);
    k_pred<<<NGRAPH, 256, 0, stream>>>(pb2, hw3, hb3, out);
}

// Round 8
// 463.726 us; speedup vs baseline: 3.0389x; 1.0684x over previous
//
#include <hip/hip_runtime.h>

#define NODES 16000
#define EDGES 256000
#define EMB   300
#define KP1   320      // padded EMB (mult of 32)
#define NP1   640      // padded 2*EMB (mult of 64)
#define NP2B  384      // padded rows for w2bT (3 x 128 tiles)
#define NGRAPH 64
#define LAYERS 5
#define INV_N (1.0f / 16000.0f)

typedef unsigned short u16;
typedef unsigned int u32;
typedef __bf16 bf16_t;
typedef bf16_t bf16x8 __attribute__((ext_vector_type(8)));
typedef float f32x4 __attribute__((ext_vector_type(4)));

__device__ inline u16 f2bf(float f) {
    bf16_t b = (bf16_t)f;
    return __builtin_bit_cast(u16, b);
}
__device__ inline float bf_lo(u32 u) { return __builtin_bit_cast(float, u << 16); }
__device__ inline float bf_hi(u32 u) { return __builtin_bit_cast(float, u & 0xFFFF0000u); }
__device__ inline u32 bf_pack(float lo, float hi) {
    return ((u32)f2bf(hi) << 16) | (u32)f2bf(lo);
}

__device__ inline float softplus_f(float x) {
    return fmaxf(x, 0.f) + log1pf(expf(-fabsf(x)));
}

// async global->LDS, 16B per lane; LDS dest is wave-uniform base + lane*16
__device__ inline void gload_lds16(const u16* g, u16* l) {
    __builtin_amdgcn_global_load_lds(
        (const __attribute__((address_space(1))) void*)g,
        (__attribute__((address_space(3))) void*)l, 16, 0, 0);
}

// BN affine from raw moments: y = x*s + t
__device__ inline void bn_coef_v(float ss, float qq, float gg, float bb,
                                 float& s, float& t) {
    float mean = ss * INV_N;
    float var = qq * INV_N - mean * mean;
    float rstd = rsqrtf(var + 1e-5f);
    s = rstd * gg;
    t = bb - mean * s;
}

// ---------------- CSR build (real edges only; self-loops analytic) -------------
__global__ void k_count(const int* __restrict__ ei, int* __restrict__ cnt) {
    int e = blockIdx.x * 256 + threadIdx.x;
    if (e >= EDGES) return;
    atomicAdd(&cnt[ei[EDGES + e]], 1);
}

// 1024 threads, 16 nodes/thread; wave shuffle-scan + LDS wave-prefix, 1 barrier.
__global__ __launch_bounds__(1024) void k_scan(const int* __restrict__ cnt,
                                               int* __restrict__ row_off,
                                               int* __restrict__ cursor) {
    __shared__ int wsum[16];
    int t = threadIdx.x;
    int lane = t & 63, w = t >> 6;
    int base = t * 16;
    int pre[16];
    int run = 0;
#pragma unroll
    for (int i = 0; i < 16; ++i) {
        int idx = base + i;
        int v = (idx < NODES) ? cnt[idx] : 0;
        pre[i] = run;
        run += v;
    }
    int inc = run;
#pragma unroll
    for (int off = 1; off < 64; off <<= 1) {
        int n = __shfl_up(inc, off);
        if (lane >= off) inc += n;
    }
    if (lane == 63) wsum[w] = inc;
    __syncthreads();
    int wpre = 0;
    for (int i = 0; i < w; ++i) wpre += wsum[i];
    int excl = wpre + inc - run;
#pragma unroll
    for (int i = 0; i < 16; ++i) {
        int idx = base + i;
        if (idx < NODES) {
            int st = excl + pre[i];
            row_off[idx] = st;
            cursor[idx] = st;
        }
    }
    if (t == 1023) row_off[NODES] = wpre + inc;
}

__global__ void k_fill(const int* __restrict__ ei, const int* __restrict__ ea,
                       int* __restrict__ cursor, int* __restrict__ packed) {
    int e = blockIdx.x * 256 + threadIdx.x;
    if (e >= EDGES) return;
    int src = ei[e];
    int dst = ei[EDGES + e];
    int c = ea[e * 2] * 3 + ea[e * 2 + 1];
    int pos = atomicAdd(&cursor[dst], 1);
    packed[pos] = src | (c << 20);
}

// ---------------- fused setup: embed | comb | convw1 | convw2 | goff ----------
#define SEG0 1200000   // embed: NODES*EMB/4
#define SEG1 6750      // comb: 5*18*75
#define SEG2 256000    // convw1: 5*640*80
#define SEG3 307200    // convw2: 5*384*160
#define SETUP_TOT (SEG0 + SEG1 + SEG2 + SEG3 + NGRAPH + 1)

__global__ __launch_bounds__(256) void k_setup(
    const int* __restrict__ x, const float* __restrict__ e1x,
    const float* __restrict__ e2x, const float* __restrict__ ce1,
    const float* __restrict__ ce2, const float* __restrict__ w1,
    const float* __restrict__ w2, const int* __restrict__ batch,
    u16* __restrict__ h, u16* __restrict__ comb,
    u16* __restrict__ w1bT, u16* __restrict__ w2bT, int* __restrict__ goff) {
    int id = blockIdx.x * 256 + threadIdx.x;
    if (id < SEG0) {
        int base = id * 4;
        int row = base / EMB;
        int f = base - row * EMB;
        int x1 = x[2 * row], x2 = x[2 * row + 1];
        float4 a = *(const float4*)(e1x + x1 * EMB + f);
        float4 b = *(const float4*)(e2x + x2 * EMB + f);
        u32* o = (u32*)h + id * 2;
        o[0] = bf_pack(a.x + b.x, a.y + b.y);
        o[1] = bf_pack(a.z + b.z, a.w + b.w);
        return;
    }
    id -= SEG0;
    if (id < SEG1) {
        int l = id / 1350, r = id - l * 1350;
        int c = r / 75, f = (r - c * 75) * 4;
        int a = c / 3, bb = c - a * 3;
        float4 va = *(const float4*)(ce1 + (l * 6 + a) * EMB + f);
        float4 vb = *(const float4*)(ce2 + (l * 3 + bb) * EMB + f);
        u32* o = (u32*)comb + ((l * 18 + c) * EMB + f) / 2;
        o[0] = bf_pack(va.x + vb.x, va.y + vb.y);
        o[1] = bf_pack(va.z + vb.z, va.w + vb.w);
        return;
    }
    id -= SEG1;
    if (id < SEG2) {  // w1bT[l][n][k] = w1[l][k][n], pad to [640][320]
        int l = id / (NP1 * 80), r = id - l * (NP1 * 80);
        int n = r / 80, k4 = (r - n * 80) * 4;
        float v[4];
#pragma unroll
        for (int j = 0; j < 4; ++j) {
            int k = k4 + j;
            v[j] = (n < 600 && k < EMB) ? w1[(l * EMB + k) * 600 + n] : 0.f;
        }
        u32* o = (u32*)w1bT + ((size_t)(l * NP1 + n) * KP1 + k4) / 2;
        o[0] = bf_pack(v[0], v[1]);
        o[1] = bf_pack(v[2], v[3]);
        return;
    }
    id -= SEG2;
    if (id < SEG3) {  // w2bT[l][n][k] = w2[l][k][n], pad to [384][640]
        int l = id / (NP2B * 160), r = id - l * (NP2B * 160);
        int n = r / 160, k4 = (r - n * 160) * 4;
        float v[4];
#pragma unroll
        for (int j = 0; j < 4; ++j) {
            int k = k4 + j;
            v[j] = (n < EMB && k < 600) ? w2[(l * 600 + k) * EMB + n] : 0.f;
        }
        u32* o = (u32*)w2bT + ((size_t)(l * NP2B + n) * NP1 + k4) / 2;
        o[0] = bf_pack(v[0], v[1]);
        o[1] = bf_pack(v[2], v[3]);
        return;
    }
    id -= SEG3;
    if (id <= NGRAPH) {
        int lo = 0, hi = NODES;
        while (lo < hi) { int mid = (lo + hi) >> 1; if (batch[mid] < id) lo = mid + 1; else hi = mid; }
        goff[id] = lo;
    }
}

// ---------------- BN+relu hoisted: h' = relu(h*s + t), bf16->bf16, 4 elems/thr -
__global__ __launch_bounds__(256) void k_bnrelu(
    const u16* __restrict__ hin, u16* __restrict__ hout,
    const float* __restrict__ ssum, const float* __restrict__ ssq,
    const float* __restrict__ g, const float* __restrict__ b) {
    int id = blockIdx.x * 256 + threadIdx.x;
    if (id >= NODES * EMB / 4) return;
    int base = id * 4;
    int row = base / EMB;
    int f = base - row * EMB;  // f % 4 == 0 since 4 | 300
    float4 S = *(const float4*)(ssum + f);
    float4 Q = *(const float4*)(ssq + f);
    float4 G = *(const float4*)(g + f);
    float4 B = *(const float4*)(b + f);
    const u32* in = (const u32*)hin + id * 2;
    u32 x0 = in[0], x1 = in[1];
    float sc0, tc0, sc1, tc1, sc2, tc2, sc3, tc3;
    bn_coef_v(S.x, Q.x, G.x, B.x, sc0, tc0);
    bn_coef_v(S.y, Q.y, G.y, B.y, sc1, tc1);
    bn_coef_v(S.z, Q.z, G.z, B.z, sc2, tc2);
    bn_coef_v(S.w, Q.w, G.w, B.w, sc3, tc3);
    float v0 = fmaxf(bf_lo(x0) * sc0 + tc0, 0.f);
    float v1 = fmaxf(bf_hi(x0) * sc1 + tc1, 0.f);
    float v2 = fmaxf(bf_lo(x1) * sc2 + tc2, 0.f);
    float v3 = fmaxf(bf_hi(x1) * sc3 + tc3, 0.f);
    u32* o = (u32*)hout + id * 2;
    o[0] = bf_pack(v0, v1);
    o[1] = bf_pack(v2, v3);
}

// ---------------- aggregation: one wave per node, scalar edge bases ------------
// Per edge: packed word readfirstlane'd to SGPR -> h/comb row bases are scalar;
// loads are s[base] + lane*4 (+imm). Self-loop (h[node] + comb[15]) in the init.
#define AGG_E(Q)                                                \
    {                                                           \
        const u32* hr = hu + (size_t)((Q) & 0xFFFFF) * 150;     \
        const u32* cr = cu + ((Q) >> 20) * 150;                 \
        u32 u0 = hr[lane], u1 = hr[64 + lane];                  \
        u32 v0 = cr[lane], v1 = cr[64 + lane];                  \
        u32 u2 = 0, v2 = 0;                                     \
        if (has2) { u2 = hr[128 + lane]; v2 = cr[128 + lane]; } \
        a0l += bf_lo(u0) + bf_lo(v0);                           \
        a0h += bf_hi(u0) + bf_hi(v0);                           \
        a1l += bf_lo(u1) + bf_lo(v1);                           \
        a1h += bf_hi(u1) + bf_hi(v1);                           \
        a2l += bf_lo(u2) + bf_lo(v2);                           \
        a2h += bf_hi(u2) + bf_hi(v2);                           \
    }

__global__ __launch_bounds__(256) void k_aggregate(
    const u16* __restrict__ h, const int* __restrict__ row_off,
    const int* __restrict__ packed, const u16* __restrict__ comb,
    u16* __restrict__ aggB) {
    int node = blockIdx.x * 4 + (threadIdx.x >> 6);
    int lane = threadIdx.x & 63;
    int s = row_off[node], e = row_off[node + 1];
    bool has2 = lane < 22;  // features 256..299 = 22 uint pairs
    const u32* hu = (const u32*)h;
    const u32* cu = (const u32*)comb;
    float a0l = 0, a0h = 0, a1l = 0, a1h = 0, a2l = 0, a2h = 0;
    // self-loop: h[node] + comb[15]  (attr (5,0) -> 5*3+0)
    {
        const u32* hr = hu + (size_t)node * 150;
        const u32* cr = cu + 15 * 150;
        u32 u0 = hr[lane], u1 = hr[64 + lane];
        u32 v0 = cr[lane], v1 = cr[64 + lane];
        u32 u2 = 0, v2 = 0;
        if (has2) { u2 = hr[128 + lane]; v2 = cr[128 + lane]; }
        a0l = bf_lo(u0) + bf_lo(v0);
        a0h = bf_hi(u0) + bf_hi(v0);
        a1l = bf_lo(u1) + bf_lo(v1);
        a1h = bf_hi(u1) + bf_hi(v1);
        a2l = bf_lo(u2) + bf_lo(v2);
        a2h = bf_hi(u2) + bf_hi(v2);
    }
    int p = s;
    for (; p + 3 < e; p += 4) {
        int q0 = __builtin_amdgcn_readfirstlane(packed[p]);
        int q1 = __builtin_amdgcn_readfirstlane(packed[p + 1]);
        int q2 = __builtin_amdgcn_readfirstlane(packed[p + 2]);
        int q3 = __builtin_amdgcn_readfirstlane(packed[p + 3]);
        AGG_E(q0); AGG_E(q1); AGG_E(q2); AGG_E(q3);
    }
    for (; p < e; ++p) {
        int q = __builtin_amdgcn_readfirstlane(packed[p]);
        AGG_E(q);
    }
    u32* o = (u32*)(aggB + (size_t)node * KP1);
    o[lane] = bf_pack(a0l, a0h);
    o[64 + lane] = bf_pack(a1l, a1h);
    if (lane < 32) o[128 + lane] = has2 ? bf_pack(a2l, a2h) : 0u;  // pads 300..319
}

// ---------------- bf16 MFMA GEMM, 128x128 tile, global_load_lds staging --------
// m97 structure: linear LDS [128][32] u16, 2 barriers/K-step, 16 MFMA/step.
// grid (N/128, M/128): N-tile on x (fastest) so consecutive blocks share A panel.
// MODE 0: +bias, relu, bf16 store (ldc stride)
// MODE 1: +bias, bf16 store (EMB stride, col<300) + fused column stats
template <int MODE>
__global__ __launch_bounds__(256) void k_gemm(
    const u16* __restrict__ A, const u16* __restrict__ Bt,
    const float* __restrict__ bias, int nbias,
    u16* __restrict__ Cv, int ldc, int K,
    float* __restrict__ ssum, float* __restrict__ ssq) {
    __shared__ __align__(16) u16 Al[128 * 32];
    __shared__ __align__(16) u16 Bl[128 * 32];
    __shared__ float rs[2][128];
    __shared__ float rq[2][128];
    int t = threadIdx.x;
    int n0 = blockIdx.x * 128, m0 = blockIdx.y * 128;
    int lane = t & 63, w = t >> 6;
    int wr = w >> 1, wc = w & 1;
    int lr = lane >> 2, lc = lane & 3;
    const u16* gA0 = A + (size_t)(m0 + w * 32 + lr) * K + lc * 8;
    const u16* gA1 = gA0 + (size_t)16 * K;
    const u16* gB0 = Bt + (size_t)(n0 + w * 32 + lr) * K + lc * 8;
    const u16* gB1 = gB0 + (size_t)16 * K;
    u16* lA0 = &Al[(w * 32) * 32];
    u16* lA1 = &Al[(w * 32 + 16) * 32];
    u16* lB0 = &Bl[(w * 32) * 32];
    u16* lB1 = &Bl[(w * 32 + 16) * 32];
    f32x4 acc[4][4];
#pragma unroll
    for (int i = 0; i < 4; i++)
#pragma unroll
        for (int j = 0; j < 4; j++) acc[i][j] = (f32x4){0.f, 0.f, 0.f, 0.f};
    int fr = lane & 15;
    int k0 = (lane >> 4) * 8;
    int abase = (wr * 64 + fr) * 32 + k0;
    int bbase = (wc * 64 + fr) * 32 + k0;
    for (int kt = 0; kt < K; kt += 32) {
        if (kt) __syncthreads();
        gload_lds16(gA0 + kt, lA0);
        gload_lds16(gA1 + kt, lA1);
        gload_lds16(gB0 + kt, lB0);
        gload_lds16(gB1 + kt, lB1);
        __syncthreads();
        bf16x8 af[4], bfv[4];
#pragma unroll
        for (int f = 0; f < 4; ++f) {
            af[f]  = *reinterpret_cast<const bf16x8*>(&Al[abase + f * 16 * 32]);
            bfv[f] = *reinterpret_cast<const bf16x8*>(&Bl[bbase + f * 16 * 32]);
        }
#pragma unroll
        for (int fm = 0; fm < 4; ++fm)
#pragma unroll
            for (int fn = 0; fn < 4; ++fn)
                acc[fm][fn] = __builtin_amdgcn_mfma_f32_16x16x32_bf16(
                    af[fm], bfv[fn], acc[fm][fn], 0, 0, 0);
    }
    int rg = lane >> 4;
    if (MODE == 0) {
#pragma unroll
        for (int fn = 0; fn < 4; ++fn) {
            int col = n0 + wc * 64 + fn * 16 + fr;
            float bv = (col < nbias) ? bias[col] : 0.f;
#pragma unroll
            for (int fm = 0; fm < 4; ++fm) {
                int rb = m0 + wr * 64 + fm * 16 + rg * 4;
#pragma unroll
                for (int j = 0; j < 4; ++j) {
                    float v = fmaxf(acc[fm][fn][j] + bv, 0.f);
                    Cv[(size_t)(rb + j) * ldc + col] = f2bf(v);
                }
            }
        }
    } else {
#pragma unroll
        for (int fn = 0; fn < 4; ++fn) {
            int col = n0 + wc * 64 + fn * 16 + fr;
            float bv = (col < nbias) ? bias[col] : 0.f;
            float cs = 0.f, cq = 0.f;
#pragma unroll
            for (int fm = 0; fm < 4; ++fm) {
                int rb = m0 + wr * 64 + fm * 16 + rg * 4;
#pragma unroll
                for (int j = 0; j < 4; ++j) {
                    float v = acc[fm][fn][j] + bv;
                    if (col < EMB) Cv[(size_t)(rb + j) * EMB + col] = f2bf(v);
                    cs += v;
                    cq += v * v;
                }
            }
            cs += __shfl_xor(cs, 16); cs += __shfl_xor(cs, 32);
            cq += __shfl_xor(cq, 16); cq += __shfl_xor(cq, 32);
            if (rg == 0) {
                rs[wr][wc * 64 + fn * 16 + fr] = cs;
                rq[wr][wc * 64 + fn * 16 + fr] = cq;
            }
        }
        __syncthreads();
        if (t < 128) {
            int col = n0 + t;
            if (col < EMB) {
                atomicAdd(&ssum[col], rs[0][t] + rs[1][t]);
                atomicAdd(&ssq[col], rq[0][t] + rq[1][t]);
            }
        }
    }
}

// ---------------- tail: pool (fused final BN), head GEMMs ----------------------
__global__ __launch_bounds__(256) void k_pool(const u16* __restrict__ h,
                                              const int* __restrict__ goff,
                                              const float* __restrict__ ssum,
                                              const float* __restrict__ ssq,
                                              const float* __restrict__ bng,
                                              const float* __restrict__ bnb,
                                              float* __restrict__ hg) {
    __shared__ float red[4][64];
    int g = blockIdx.x;
    int col = blockIdx.y * 64 + (threadIdx.x & 63);
    int w = threadIdx.x >> 6;
    int s = goff[g], e = goff[g + 1];
    float a = 0.f;
    bool ok = col < EMB;
    if (ok) {
        for (int r = s + w; r < e; r += 4)
            a += __builtin_bit_cast(float, (u32)h[(size_t)r * EMB + col] << 16);
    }
    red[w][threadIdx.x & 63] = a;
    __syncthreads();
    if (w == 0 && ok) {
        float sc, tc;
        bn_coef_v(ssum[col], ssq[col], bng[col], bnb[col], sc, tc);
        float v = red[0][threadIdx.x] + red[1][threadIdx.x] +
                  red[2][threadIdx.x] + red[3][threadIdx.x];
        float inv = (e > s) ? 1.0f / (float)(e - s) : 0.f;
        hg[(size_t)g * EMB + col] = (v * inv) * sc + tc;
    }
}

template <int ACT>  // 0: none, 1: softplus
__global__ __launch_bounds__(256) void k_small_mm(
    const float* __restrict__ A, const float* __restrict__ W,
    const float* __restrict__ bias, float* __restrict__ C, int N, int K) {
    __shared__ float red[4][64];
    int row = blockIdx.x;
    int lane = threadIdx.x & 63;
    int col = blockIdx.y * 64 + lane;
    int w = threadIdx.x >> 6;
    const float* a = A + (size_t)row * K;
    float acc = 0.f;
#pragma unroll 4
    for (int k = w; k < K; k += 4) acc += a[k] * W[(size_t)k * N + col];
    red[w][lane] = acc;
    __syncthreads();
    if (w == 0) {
        float v = red[0][lane] + red[1][lane] + red[2][lane] + red[3][lane] + bias[col];
        if (ACT) v = softplus_f(v);
        C[(size_t)row * N + col] = v;
    }
}

__global__ __launch_bounds__(256) void k_pred(const float* __restrict__ P,
                                              const float* __restrict__ hw3,
                                              const float* __restrict__ hb3,
                                              float* __restrict__ out) {
    __shared__ float red[2][4];
    int g = blockIdx.x;
    int t = threadIdx.x;
    float q = P[(size_t)g * 256 + t];
    float r0 = q * hw3[t * 2 + 0];
    float r1 = q * hw3[t * 2 + 1];
#pragma unroll
    for (int off = 32; off > 0; off >>= 1) {
        r0 += __shfl_down(r0, off);
        r1 += __shfl_down(r1, off);
    }
    if ((t & 63) == 0) { red[0][t >> 6] = r0; red[1][t >> 6] = r1; }
    __syncthreads();
    if (t == 0) {
        out[(size_t)NGRAPH * 512 + g * 2 + 0] = red[0][0] + red[0][1] + red[0][2] + red[0][3] + hb3[0];
        out[(size_t)NGRAPH * 512 + g * 2 + 1] = red[1][0] + red[1][1] + red[1][2] + red[1][3] + hb3[1];
    }
}

// ---------------- launch ----------------
extern "C" void kernel_launch(void* const* d_in, const int* in_sizes, int n_in,
                              void* d_out, int out_size, void* d_ws, size_t ws_size,
                              hipStream_t stream) {
    const int* x      = (const int*)d_in[0];
    const int* ei     = (const int*)d_in[1];
    const int* ea     = (const int*)d_in[2];
    const int* batch  = (const int*)d_in[3];
    const float* x_emb1 = (const float*)d_in[4];
    const float* x_emb2 = (const float*)d_in[5];
    const float* e1_emb = (const float*)d_in[6];
    const float* e2_emb = (const float*)d_in[7];
    const float* w1   = (const float*)d_in[8];
    const float* b1   = (const float*)d_in[9];
    const float* w2   = (const float*)d_in[10];
    const float* b2   = (const float*)d_in[11];
    const float* bn_g = (const float*)d_in[12];
    const float* bn_b = (const float*)d_in[13];
    const float* feat_w = (const float*)d_in[14];
    const float* feat_b = (const float*)d_in[15];
    const float* hw1  = (const float*)d_in[16];
    const float* hb1  = (const float*)d_in[17];
    const float* hw2  = (const float*)d_in[18];
    const float* hb2  = (const float*)d_in[19];
    const float* hw3  = (const float*)d_in[20];
    const float* hb3  = (const float*)d_in[21];
    float* out = (float*)d_out;

    char* p = (char*)d_ws;
    auto alloc = [&](size_t bytes) -> char* {
        char* r = p;
        p += ((bytes + 255) / 256) * 256;
        return r;
    };
    u16* h_a     = (u16*)alloc((size_t)NODES * EMB * 2);   // current h (pre-BN)
    u16* h_b     = (u16*)alloc((size_t)NODES * EMB * 2);   // post-BN h'
    u16* aggB    = (u16*)alloc((size_t)NODES * KP1 * 2);
    u16* T       = (u16*)alloc((size_t)NODES * NP1 * 2);
    u16* w1bT    = (u16*)alloc((size_t)LAYERS * NP1 * KP1 * 2);
    u16* w2bT    = (u16*)alloc((size_t)LAYERS * NP2B * NP1 * 2);
    u16* comb    = (u16*)alloc((size_t)LAYERS * 18 * EMB * 2);
    int* row_off = (int*)alloc((NODES + 1) * 4);
    int* packed  = (int*)alloc((size_t)EDGES * 4);
    int* goff    = (int*)alloc((NGRAPH + 1) * 4);
    float* hg    = (float*)alloc((size_t)NGRAPH * EMB * 4);
    float* pb1   = (float*)alloc((size_t)NGRAPH * 256 * 4);
    float* pb2   = (float*)alloc((size_t)NGRAPH * 256 * 4);
    // cursor + per-layer stats contiguous -> single memset
    int* cursor  = (int*)alloc(NODES * 4);                 // 64000 B (256-mult)
    float* stats5 = (float*)alloc((size_t)LAYERS * 640 * 4);  // [l][ssum320|ssq320]
    if ((size_t)(p - (char*)d_ws) > ws_size) return;  // workspace too small

    hipMemsetAsync(cursor, 0, NODES * 4 + LAYERS * 640 * 4, stream);

    // CSR build (real edges only; self-loops analytic in k_aggregate)
    k_count<<<(EDGES + 255) / 256, 256, 0, stream>>>(ei, cursor);
    k_scan<<<1, 1024, 0, stream>>>(cursor, row_off, cursor);
    k_fill<<<(EDGES + 255) / 256, 256, 0, stream>>>(ei, ea, cursor, packed);

    // fused setup: embed -> h_a, comb, w1bT, w2bT, goff
    k_setup<<<(SETUP_TOT + 255) / 256, 256, 0, stream>>>(
        x, x_emb1, x_emb2, e1_emb, e2_emb, w1, w2, batch,
        h_a, comb, w1bT, w2bT, goff);

    for (int l = 0; l < LAYERS; ++l) {
        const u16* h_src;
        if (l == 0) {
            h_src = h_a;
        } else {
            float* st = stats5 + (size_t)(l - 1) * 640;
            k_bnrelu<<<(NODES * EMB / 4 + 255) / 256, 256, 0, stream>>>(
                h_a, h_b, st, st + 320, bn_g + (l - 1) * EMB, bn_b + (l - 1) * EMB);
            h_src = h_b;
        }
        k_aggregate<<<NODES / 4, 256, 0, stream>>>(
            h_src, row_off, packed, comb + (size_t)l * 18 * EMB, aggB);
        k_gemm<0><<<dim3(NP1 / 128, NODES / 128), 256, 0, stream>>>(
            aggB, w1bT + (size_t)l * NP1 * KP1, b1 + l * 600, 600, T, NP1, KP1,
            nullptr, nullptr);
        float* st = stats5 + (size_t)l * 640;
        k_gemm<1><<<dim3(NP2B / 128, NODES / 128), 256, 0, stream>>>(
            T, w2bT + (size_t)l * NP2B * NP1, b2 + l * EMB, EMB, h_a, 0, NP1,
            st, st + 320);
    }

    // h_a holds layer-4 pre-BN output; pool applies BN affine post-mean
    float* st4 = stats5 + (size_t)4 * 640;
    k_pool<<<dim3(NGRAPH, 5), 256, 0, stream>>>(h_a, goff, st4, st4 + 320,
                                                bn_g + 4 * EMB, bn_b + 4 * EMB, hg);
    k_small_mm<0><<<dim3(NGRAPH, 8), 256, 0, stream>>>(hg, feat_w, feat_b, out, 512, EMB);
    k_small_mm<1><<<dim3(NGRAPH, 4), 256, 0, stream>>>(out, hw1, hb1, pb1, 256, 512);
    k_small_mm<1><<<dim3(NGRAPH, 4), 256, 0, stream>>>(pb1, hw2, hb2, pb2, 256, 256);
    k_pred<<<NGRAPH, 256, 0, stream>>>(pb2, hw3, hb3, out);
}